// Round 3
// baseline (227.838 us; speedup 1.0000x reference)
//
#include <hip/hip_runtime.h>
#include <hip/hip_bf16.h>
#include <hip/hip_fp16.h>

typedef _Float16 f16x8 __attribute__((ext_vector_type(8)));
typedef _Float16 f16x4 __attribute__((ext_vector_type(4)));
typedef float    f32x4 __attribute__((ext_vector_type(4)));
typedef short    s16x8 __attribute__((ext_vector_type(8)));

#define LDK 40  // padded LDS K-stride in halves (80 B, breaks pow2 bank pattern)

// ---------------------------------------------------------------------------
// Kernel 1: QKV projection. C = x(fp32)[16384x512] @ W(fp32)[512x512] per matrix.
// blockIdx.x in [0,12): 4 col-blocks each for Q,K,V. blockIdx.y: 128 row-blocks.
// Q,K written fp16 row-major [16384][512]. V written transposed [b][512][2048].
// ---------------------------------------------------------------------------
__global__ __launch_bounds__(256)
void proj_kernel(const float* __restrict__ x,
                 const float* __restrict__ Wq,
                 const float* __restrict__ Wk,
                 const float* __restrict__ Wv,
                 _Float16* __restrict__ Qf,
                 _Float16* __restrict__ Kf,
                 _Float16* __restrict__ Vt)
{
    __shared__ _Float16 a_lds[128][LDK];
    __shared__ _Float16 b_lds[128][LDK];

    const int tid = threadIdx.x;
    const int cb  = blockIdx.x;          // 0..11
    const int mb  = blockIdx.y;          // 0..127
    const int mat = cb >> 2;             // 0=Q 1=K 2=V
    const int nb  = cb & 3;
    const float* W = (mat == 0) ? Wq : (mat == 1) ? Wk : Wv;
    const int m0 = mb * 128;
    const int n0 = nb * 128;

    const int lane = tid & 63;
    const int w    = tid >> 6;
    const int wr   = w >> 1, wc = w & 1;
    const int lrow = lane & 15, lkg = lane >> 4;

    f32x4 acc[4][4];
#pragma unroll
    for (int i = 0; i < 4; i++)
#pragma unroll
        for (int j = 0; j < 4; j++) acc[i][j] = (f32x4)0.0f;

    const int ar = tid >> 1;             // 0..127 (x row in tile)
    const int ah = tid & 1;              // which 16-wide half of BK
    const int bcol = tid & 127;          // W column in tile
    const int bkq  = (tid >> 7) * 16;    // k half

    for (int k0 = 0; k0 < 512; k0 += 32) {
        // stage A: x tile 128x32, fp32 -> fp16
        {
            const float* src = x + (size_t)(m0 + ar) * 512 + k0 + ah * 16;
#pragma unroll
            for (int i = 0; i < 4; i++) {
                f32x4 v = *(const f32x4*)(src + 4 * i);
                f16x4 h;
#pragma unroll
                for (int j = 0; j < 4; j++) h[j] = (_Float16)v[j];
                *(f16x4*)&a_lds[ar][ah * 16 + 4 * i] = h;
            }
        }
        // stage B: W tile 32x128 -> LDS transposed [col][k]
        {
            const float* wsrc = W + (size_t)(k0 + bkq) * 512 + n0 + bcol;
#pragma unroll
            for (int j4 = 0; j4 < 4; j4++) {
                f16x4 h;
#pragma unroll
                for (int j = 0; j < 4; j++) h[j] = (_Float16)wsrc[(size_t)(j4 * 4 + j) * 512];
                *(f16x4*)&b_lds[bcol][bkq + j4 * 4] = h;
            }
        }
        __syncthreads();

        f16x8 af[4], bf[4];
#pragma unroll
        for (int mi = 0; mi < 4; mi++)
            af[mi] = *(const f16x8*)&a_lds[wr * 64 + mi * 16 + lrow][lkg * 8];
#pragma unroll
        for (int ni = 0; ni < 4; ni++)
            bf[ni] = *(const f16x8*)&b_lds[wc * 64 + ni * 16 + lrow][lkg * 8];
#pragma unroll
        for (int mi = 0; mi < 4; mi++)
#pragma unroll
            for (int ni = 0; ni < 4; ni++)
                acc[mi][ni] = __builtin_amdgcn_mfma_f32_16x16x32_f16(af[mi], bf[ni], acc[mi][ni], 0, 0, 0);
        __syncthreads();
    }

    if (mat < 2) {
        _Float16* Out = (mat == 0) ? Qf : Kf;
#pragma unroll
        for (int mi = 0; mi < 4; mi++) {
            const int mbase = m0 + wr * 64 + mi * 16 + lkg * 4;
#pragma unroll
            for (int ni = 0; ni < 4; ni++) {
                const int ncol = n0 + wc * 64 + ni * 16 + lrow;
#pragma unroll
                for (int r = 0; r < 4; r++)
                    Out[(size_t)(mbase + r) * 512 + ncol] = (_Float16)acc[mi][ni][r];
            }
        }
    } else {
        // V transposed: Vt[b][d][m], 4 consecutive m per lane -> 8B store
#pragma unroll
        for (int mi = 0; mi < 4; mi++) {
            const int mglob = m0 + wr * 64 + mi * 16 + lkg * 4;
            const int b = mglob >> 11, mloc = mglob & 2047;
#pragma unroll
            for (int ni = 0; ni < 4; ni++) {
                const int d = n0 + wc * 64 + ni * 16 + lrow;
                f16x4 h;
#pragma unroll
                for (int r = 0; r < 4; r++) h[r] = (_Float16)acc[mi][ni][r];
                *(f16x4*)&Vt[((size_t)b * 512 + d) * 2048 + mloc] = h;
            }
        }
    }
}

// ---------------------------------------------------------------------------
// Kernel 2: S = Q @ K^T. fp16 in, fp32 scores out (chunk-local batches).
// grid: (m-block 16, n-block 16, nbatch). b0 = global batch offset.
// ---------------------------------------------------------------------------
__global__ __launch_bounds__(256)
void score_kernel(const _Float16* __restrict__ Qf,
                  const _Float16* __restrict__ Kf,
                  float* __restrict__ S, int b0)
{
    __shared__ _Float16 a_lds[128][LDK];
    __shared__ _Float16 b_lds[128][LDK];

    const int tid = threadIdx.x;
    const int mb = blockIdx.x, nb = blockIdx.y, bl = blockIdx.z;
    const int bg = b0 + bl;

    const _Float16* Abase = Qf + (size_t)(bg * 2048 + nb * 128) * 512;
    const _Float16* Bbase = Kf + (size_t)(bg * 2048 + mb * 128) * 512;

    const int lane = tid & 63;
    const int w    = tid >> 6;
    const int wr   = w >> 1, wc = w & 1;
    const int lrow = lane & 15, lkg = lane >> 4;

    f32x4 acc[4][4];
#pragma unroll
    for (int i = 0; i < 4; i++)
#pragma unroll
        for (int j = 0; j < 4; j++) acc[i][j] = (f32x4)0.0f;

    const int r  = tid >> 1;
    const int hf = tid & 1;

    for (int k0 = 0; k0 < 512; k0 += 32) {
        const _Float16* asrc = Abase + (size_t)r * 512 + k0 + hf * 16;
        const _Float16* bsrc = Bbase + (size_t)r * 512 + k0 + hf * 16;
        *(s16x8*)&a_lds[r][hf * 16]     = *(const s16x8*)(asrc);
        *(s16x8*)&a_lds[r][hf * 16 + 8] = *(const s16x8*)(asrc + 8);
        *(s16x8*)&b_lds[r][hf * 16]     = *(const s16x8*)(bsrc);
        *(s16x8*)&b_lds[r][hf * 16 + 8] = *(const s16x8*)(bsrc + 8);
        __syncthreads();

        f16x8 af[4], bf[4];
#pragma unroll
        for (int mi = 0; mi < 4; mi++)
            af[mi] = *(const f16x8*)&a_lds[wr * 64 + mi * 16 + lrow][lkg * 8];
#pragma unroll
        for (int ni = 0; ni < 4; ni++)
            bf[ni] = *(const f16x8*)&b_lds[wc * 64 + ni * 16 + lrow][lkg * 8];
#pragma unroll
        for (int mi = 0; mi < 4; mi++)
#pragma unroll
            for (int ni = 0; ni < 4; ni++)
                acc[mi][ni] = __builtin_amdgcn_mfma_f32_16x16x32_f16(af[mi], bf[ni], acc[mi][ni], 0, 0, 0);
        __syncthreads();
    }

    float* Sb = S + (size_t)bl * 2048 * 2048;
#pragma unroll
    for (int mi = 0; mi < 4; mi++) {
        const int nbase = nb * 128 + wr * 64 + mi * 16 + lkg * 4;
#pragma unroll
        for (int ni = 0; ni < 4; ni++) {
            const int m = mb * 128 + wc * 64 + ni * 16 + lrow;
#pragma unroll
            for (int rr = 0; rr < 4; rr++)
                Sb[(size_t)(nbase + rr) * 2048 + m] = acc[mi][ni][rr];
        }
    }
}

// ---------------------------------------------------------------------------
// Kernel 3: row softmax over chunk-local S. One wave per row of 2048.
// ---------------------------------------------------------------------------
__global__ __launch_bounds__(256)
void softmax_kernel(const float* __restrict__ S, _Float16* __restrict__ A)
{
    const int row  = blockIdx.x * 4 + (threadIdx.x >> 6);
    const int lane = threadIdx.x & 63;
    const float* srow = S + (size_t)row * 2048;
    _Float16*    arow = A + (size_t)row * 2048;

    f32x4 v[8];
    float mx = -3.4e38f;
#pragma unroll
    for (int i = 0; i < 8; i++) {
        v[i] = *(const f32x4*)(srow + i * 256 + lane * 4);
        mx = fmaxf(mx, fmaxf(fmaxf(v[i][0], v[i][1]), fmaxf(v[i][2], v[i][3])));
    }
#pragma unroll
    for (int off = 32; off; off >>= 1) mx = fmaxf(mx, __shfl_xor(mx, off));

    float s = 0.0f;
#pragma unroll
    for (int i = 0; i < 8; i++) {
#pragma unroll
        for (int j = 0; j < 4; j++) {
            float e = exp2f((v[i][j] - mx) * 1.44269504f);
            v[i][j] = e;
            s += e;
        }
    }
#pragma unroll
    for (int off = 32; off; off >>= 1) s += __shfl_xor(s, off);
    const float inv = 1.0f / s;

#pragma unroll
    for (int i = 0; i < 8; i++) {
        f16x4 h;
#pragma unroll
        for (int j = 0; j < 4; j++) h[j] = (_Float16)(v[i][j] * inv);
        *(f16x4*)(arow + i * 256 + lane * 4) = h;
    }
}

// ---------------------------------------------------------------------------
// Kernel 4: out = A @ V  (A fp16 chunk-local, Vt fp16 [b][512][2048] global).
// grid: (d-block 4, n-block 16, nbatch). Output FP32 [b][2048][512].
// ---------------------------------------------------------------------------
__global__ __launch_bounds__(256)
void out_kernel(const _Float16* __restrict__ A,
                const _Float16* __restrict__ Vt,
                float* __restrict__ out, int b0)
{
    __shared__ _Float16 a_lds[128][LDK];
    __shared__ _Float16 b_lds[128][LDK];

    const int tid = threadIdx.x;
    const int db = blockIdx.x, nb = blockIdx.y, bl = blockIdx.z;
    const int bg = b0 + bl;

    const _Float16* Abase = A  + (size_t)bl * 2048 * 2048 + (size_t)(nb * 128) * 2048;
    const _Float16* Bbase = Vt + (size_t)bg * 512  * 2048 + (size_t)(db * 128) * 2048;

    const int lane = tid & 63;
    const int w    = tid >> 6;
    const int wr   = w >> 1, wc = w & 1;
    const int lrow = lane & 15, lkg = lane >> 4;

    f32x4 acc[4][4];
#pragma unroll
    for (int i = 0; i < 4; i++)
#pragma unroll
        for (int j = 0; j < 4; j++) acc[i][j] = (f32x4)0.0f;

    const int r  = tid >> 1;
    const int hf = tid & 1;

    for (int k0 = 0; k0 < 2048; k0 += 32) {
        const _Float16* asrc = Abase + (size_t)r * 2048 + k0 + hf * 16;
        const _Float16* bsrc = Bbase + (size_t)r * 2048 + k0 + hf * 16;
        *(s16x8*)&a_lds[r][hf * 16]     = *(const s16x8*)(asrc);
        *(s16x8*)&a_lds[r][hf * 16 + 8] = *(const s16x8*)(asrc + 8);
        *(s16x8*)&b_lds[r][hf * 16]     = *(const s16x8*)(bsrc);
        *(s16x8*)&b_lds[r][hf * 16 + 8] = *(const s16x8*)(bsrc + 8);
        __syncthreads();

        f16x8 af[4], bf[4];
#pragma unroll
        for (int mi = 0; mi < 4; mi++)
            af[mi] = *(const f16x8*)&a_lds[wr * 64 + mi * 16 + lrow][lkg * 8];
#pragma unroll
        for (int ni = 0; ni < 4; ni++)
            bf[ni] = *(const f16x8*)&b_lds[wc * 64 + ni * 16 + lrow][lkg * 8];
#pragma unroll
        for (int mi = 0; mi < 4; mi++)
#pragma unroll
            for (int ni = 0; ni < 4; ni++)
                acc[mi][ni] = __builtin_amdgcn_mfma_f32_16x16x32_f16(af[mi], bf[ni], acc[mi][ni], 0, 0, 0);
        __syncthreads();
    }

#pragma unroll
    for (int mi = 0; mi < 4; mi++) {
        const int nbase = nb * 128 + wr * 64 + mi * 16 + lkg * 4;
#pragma unroll
        for (int ni = 0; ni < 4; ni++) {
            const int d = db * 128 + wc * 64 + ni * 16 + lrow;
#pragma unroll
            for (int rr = 0; rr < 4; rr++)
                out[((size_t)bg * 2048 + nbase + rr) * 512 + d] = acc[mi][ni][rr];
        }
    }
}

// ---------------------------------------------------------------------------
extern "C" void kernel_launch(void* const* d_in, const int* in_sizes, int n_in,
                              void* d_out, int out_size, void* d_ws, size_t ws_size,
                              hipStream_t stream) {
    const float* x  = (const float*)d_in[0];
    const float* Wq = (const float*)d_in[1];
    const float* Wk = (const float*)d_in[2];
    const float* Wv = (const float*)d_in[3];

    const size_t MB = 1024ull * 1024ull;
    char* ws = (char*)d_ws;
    _Float16* Qf = (_Float16*)ws;                                  // 16 MB
    _Float16* Kf = Qf + (size_t)16384 * 512;                       // 16 MB
    _Float16* Vt = Kf + (size_t)16384 * 512;                       // 16 MB
    float*    S  = (float*)(Vt + (size_t)16384 * 512);             // chunk * 16 MB
    float* out = (float*)d_out;                                    // fp32 output!

    // batches per chunk, sized so 48MB + chunk*(16+8)MB + 2MB slack <= ws_size
    int chunk;
    if      (ws_size >= 242 * MB) chunk = 8;
    else if (ws_size >= 146 * MB) chunk = 4;
    else if (ws_size >= 98  * MB) chunk = 2;
    else                          chunk = 1;

    _Float16* A = (_Float16*)(S + (size_t)chunk * 2048 * 2048);    // chunk * 8 MB

    proj_kernel<<<dim3(12, 128), 256, 0, stream>>>(x, Wq, Wk, Wv, Qf, Kf, Vt);

    for (int b0 = 0; b0 < 8; b0 += chunk) {
        score_kernel<<<dim3(16, 16, chunk), 256, 0, stream>>>(Qf, Kf, S, b0);
        softmax_kernel<<<chunk * 512, 256, 0, stream>>>(S, A);
        out_kernel<<<dim3(4, 16, chunk), 256, 0, stream>>>(A, Vt, out, b0);
    }
}

// Round 4
// 186.996 us; speedup vs baseline: 1.2184x; 1.2184x over previous
//
#include <hip/hip_runtime.h>
#include <hip/hip_fp16.h>

typedef _Float16 f16x8 __attribute__((ext_vector_type(8)));
typedef _Float16 f16x4 __attribute__((ext_vector_type(4)));
typedef float    f32x4 __attribute__((ext_vector_type(4)));

// ---------------------------------------------------------------------------
// Staging: 128 rows x 64 halves fp16 tile, global row-major (ld in halves) ->
// 16 KB linear LDS via global_load_lds dwordx4. Source col is pre-swizzled
// (byte ^= (row&7)<<4) so readers apply the same XOR (rule #21: linear dest +
// inverse-swz source + swz on read).
// ---------------------------------------------------------------------------
__device__ __forceinline__ void stage128x64(const _Float16* __restrict__ g, int ld,
                                            void* lds, int tid)
{
    const int r0   = tid >> 3;                       // 0..31 (row within 32-row slab)
    const int colh = ((tid & 7) ^ (r0 & 7)) << 3;    // swizzled source col (halves)
    char* lbase = (char*)lds + (tid >> 6) * 1024;    // wave-uniform LDS base
#pragma unroll
    for (int i = 0; i < 4; i++) {
        const _Float16* src = g + (size_t)(i * 32 + r0) * ld + colh;
        __builtin_amdgcn_global_load_lds(
            (const __attribute__((address_space(1))) void*)src,
            (__attribute__((address_space(3))) void*)(lbase + i * 4096),
            16, 0, 0);
    }
}

// read 8 halves at (row, colh) from a swizzled 128x64 tile
__device__ __forceinline__ f16x8 lds_frag(const void* lds, int row, int colh)
{
    const int off = row * 128 + ((colh * 2) ^ ((row & 7) << 4));
    return *(const f16x8*)((const char*)lds + off);
}

// one BK=64 tile worth of MFMAs (2 K-steps of 32)
__device__ __forceinline__ void mfma_tile(const void* a_lds, const void* b_lds,
                                          f32x4 acc[4][4],
                                          int wr, int wc, int lrow, int lkg)
{
#pragma unroll
    for (int kk = 0; kk < 2; kk++) {
        f16x8 af[4], bf[4];
#pragma unroll
        for (int mi = 0; mi < 4; mi++)
            af[mi] = lds_frag(a_lds, wr * 64 + mi * 16 + lrow, kk * 32 + lkg * 8);
#pragma unroll
        for (int ni = 0; ni < 4; ni++)
            bf[ni] = lds_frag(b_lds, wc * 64 + ni * 16 + lrow, kk * 32 + lkg * 8);
#pragma unroll
        for (int mi = 0; mi < 4; mi++)
#pragma unroll
            for (int ni = 0; ni < 4; ni++)
                acc[mi][ni] = __builtin_amdgcn_mfma_f32_16x16x32_f16(af[mi], bf[ni], acc[mi][ni], 0, 0, 0);
    }
}

// ---------------------------------------------------------------------------
// Kernel 0: convert x -> fp16 (xh), and W{q,k,v} -> fp16 TRANSPOSED Wt[3][n][k].
// grid: 2048 blocks for x, 768 blocks (3 mats x 16x16 tiles of 32x32) for W.
// ---------------------------------------------------------------------------
__global__ __launch_bounds__(256)
void convert_kernel(const float* __restrict__ x,
                    const float* __restrict__ Wq,
                    const float* __restrict__ Wk,
                    const float* __restrict__ Wv,
                    _Float16* __restrict__ xh,
                    _Float16* __restrict__ Wt)
{
    const int b = blockIdx.x;
    if (b < 2048) {
        const size_t base = (size_t)b * 4096 + (size_t)threadIdx.x * 4;
#pragma unroll
        for (int i = 0; i < 4; i++) {
            f32x4 v = *(const f32x4*)(x + base + i * 1024);
            f16x4 h;
#pragma unroll
            for (int j = 0; j < 4; j++) h[j] = (_Float16)v[j];
            *(f16x4*)(xh + base + i * 1024) = h;
        }
    } else {
        __shared__ float tb[32][33];
        const int t = b - 2048;
        const int mat = t >> 8;
        const int tile = t & 255;
        const int tr = tile >> 4, tc = tile & 15;   // tr: k-tile, tc: n-tile
        const float* W = (mat == 0) ? Wq : (mat == 1) ? Wk : Wv;
        const int r = threadIdx.x >> 5, c = threadIdx.x & 31;
#pragma unroll
        for (int p = 0; p < 4; p++)
            tb[p * 8 + r][c] = W[(size_t)(tr * 32 + p * 8 + r) * 512 + tc * 32 + c];
        __syncthreads();
#pragma unroll
        for (int p = 0; p < 4; p++)
            Wt[((size_t)mat * 512 + tc * 32 + p * 8 + r) * 512 + tr * 32 + c] =
                (_Float16)tb[c][p * 8 + r];
    }
}

// ---------------------------------------------------------------------------
// Kernel 1: QKV projection, all-fp16. xh[16384][512] @ Wt[mat][n][k].
// Q,K row-major fp16; V transposed [b][512][2048].
// ---------------------------------------------------------------------------
__global__ __launch_bounds__(256)
void proj_kernel(const _Float16* __restrict__ xh,
                 const _Float16* __restrict__ Wt,
                 _Float16* __restrict__ Qf,
                 _Float16* __restrict__ Kf,
                 _Float16* __restrict__ Vt)
{
    __shared__ _Float16 a_lds[128 * 64];
    __shared__ _Float16 b_lds[128 * 64];

    const int tid = threadIdx.x;
    const int cb = blockIdx.x, mb = blockIdx.y;
    const int mat = cb >> 2, nb = cb & 3;
    const int m0 = mb * 128, n0 = nb * 128;

    const _Float16* Abase = xh + (size_t)m0 * 512;
    const _Float16* Bbase = Wt + ((size_t)mat * 512 + n0) * 512;

    const int lane = tid & 63;
    const int w = tid >> 6;
    const int wr = w >> 1, wc = w & 1;
    const int lrow = lane & 15, lkg = lane >> 4;

    f32x4 acc[4][4];
#pragma unroll
    for (int i = 0; i < 4; i++)
#pragma unroll
        for (int j = 0; j < 4; j++) acc[i][j] = (f32x4)0.0f;

    for (int k0 = 0; k0 < 512; k0 += 64) {
        stage128x64(Abase + k0, 512, a_lds, tid);
        stage128x64(Bbase + k0, 512, b_lds, tid);
        __syncthreads();
        mfma_tile(a_lds, b_lds, acc, wr, wc, lrow, lkg);
        __syncthreads();
    }

    if (mat < 2) {
        _Float16* Out = (mat == 0) ? Qf : Kf;
#pragma unroll
        for (int mi = 0; mi < 4; mi++) {
            const int mbase = m0 + wr * 64 + mi * 16 + lkg * 4;
#pragma unroll
            for (int ni = 0; ni < 4; ni++) {
                const int ncol = n0 + wc * 64 + ni * 16 + lrow;
#pragma unroll
                for (int r = 0; r < 4; r++)
                    Out[(size_t)(mbase + r) * 512 + ncol] = (_Float16)acc[mi][ni][r];
            }
        }
    } else {
#pragma unroll
        for (int mi = 0; mi < 4; mi++) {
            const int mglob = m0 + wr * 64 + mi * 16 + lkg * 4;
            const int b = mglob >> 11, mloc = mglob & 2047;
#pragma unroll
            for (int ni = 0; ni < 4; ni++) {
                const int d = n0 + wc * 64 + ni * 16 + lrow;
                f16x4 h;
#pragma unroll
                for (int r = 0; r < 4; r++) h[r] = (_Float16)acc[mi][ni][r];
                *(f16x4*)&Vt[((size_t)b * 512 + d) * 2048 + mloc] = h;
            }
        }
    }
}

// ---------------------------------------------------------------------------
// Kernel 2: S = Q @ K^T. grid (mb 16, nb 16, chunk).
// ---------------------------------------------------------------------------
__global__ __launch_bounds__(256)
void score_kernel(const _Float16* __restrict__ Qf,
                  const _Float16* __restrict__ Kf,
                  float* __restrict__ S, int b0)
{
    __shared__ _Float16 a_lds[128 * 64];
    __shared__ _Float16 b_lds[128 * 64];

    const int tid = threadIdx.x;
    const int mb = blockIdx.x, nb = blockIdx.y, bl = blockIdx.z;
    const int bg = b0 + bl;

    const _Float16* Abase = Qf + (size_t)(bg * 2048 + nb * 128) * 512;
    const _Float16* Bbase = Kf + (size_t)(bg * 2048 + mb * 128) * 512;

    const int lane = tid & 63;
    const int w = tid >> 6;
    const int wr = w >> 1, wc = w & 1;
    const int lrow = lane & 15, lkg = lane >> 4;

    f32x4 acc[4][4];
#pragma unroll
    for (int i = 0; i < 4; i++)
#pragma unroll
        for (int j = 0; j < 4; j++) acc[i][j] = (f32x4)0.0f;

    for (int k0 = 0; k0 < 512; k0 += 64) {
        stage128x64(Abase + k0, 512, a_lds, tid);
        stage128x64(Bbase + k0, 512, b_lds, tid);
        __syncthreads();
        mfma_tile(a_lds, b_lds, acc, wr, wc, lrow, lkg);
        __syncthreads();
    }

    float* Sb = S + (size_t)bl * 2048 * 2048;
#pragma unroll
    for (int mi = 0; mi < 4; mi++) {
        const int nbase = nb * 128 + wr * 64 + mi * 16 + lkg * 4;
#pragma unroll
        for (int ni = 0; ni < 4; ni++) {
            const int m = mb * 128 + wc * 64 + ni * 16 + lrow;
#pragma unroll
            for (int rr = 0; rr < 4; rr++)
                Sb[(size_t)(nbase + rr) * 2048 + m] = acc[mi][ni][rr];
        }
    }
}

// ---------------------------------------------------------------------------
// Kernel 3: row softmax, one wave per row of 2048 fp32 -> fp16 probs.
// ---------------------------------------------------------------------------
__global__ __launch_bounds__(256)
void softmax_kernel(const float* __restrict__ S, _Float16* __restrict__ A)
{
    const int row  = blockIdx.x * 4 + (threadIdx.x >> 6);
    const int lane = threadIdx.x & 63;
    const float* srow = S + (size_t)row * 2048;
    _Float16*    arow = A + (size_t)row * 2048;

    f32x4 v[8];
    float mx = -3.4e38f;
#pragma unroll
    for (int i = 0; i < 8; i++) {
        v[i] = *(const f32x4*)(srow + i * 256 + lane * 4);
        mx = fmaxf(mx, fmaxf(fmaxf(v[i][0], v[i][1]), fmaxf(v[i][2], v[i][3])));
    }
#pragma unroll
    for (int off = 32; off; off >>= 1) mx = fmaxf(mx, __shfl_xor(mx, off));

    float s = 0.0f;
#pragma unroll
    for (int i = 0; i < 8; i++) {
#pragma unroll
        for (int j = 0; j < 4; j++) {
            float e = exp2f((v[i][j] - mx) * 1.44269504f);
            v[i][j] = e;
            s += e;
        }
    }
#pragma unroll
    for (int off = 32; off; off >>= 1) s += __shfl_xor(s, off);
    const float inv = 1.0f / s;

#pragma unroll
    for (int i = 0; i < 8; i++) {
        f16x4 h;
#pragma unroll
        for (int j = 0; j < 4; j++) h[j] = (_Float16)(v[i][j] * inv);
        *(f16x4*)(arow + i * 256 + lane * 4) = h;
    }
}

// ---------------------------------------------------------------------------
// Kernel 4: out = A @ V. A fp16 chunk-local [2048][2048], Vt [b][512][2048].
// grid (db 4, nb 16, chunk). Output fp32 [b][2048][512].
// ---------------------------------------------------------------------------
__global__ __launch_bounds__(256)
void out_kernel(const _Float16* __restrict__ A,
                const _Float16* __restrict__ Vt,
                float* __restrict__ out, int b0)
{
    __shared__ _Float16 a_lds[128 * 64];
    __shared__ _Float16 b_lds[128 * 64];

    const int tid = threadIdx.x;
    const int db = blockIdx.x, nb = blockIdx.y, bl = blockIdx.z;
    const int bg = b0 + bl;

    const _Float16* Abase = A  + (size_t)bl * 2048 * 2048 + (size_t)(nb * 128) * 2048;
    const _Float16* Bbase = Vt + (size_t)bg * 512  * 2048 + (size_t)(db * 128) * 2048;

    const int lane = tid & 63;
    const int w = tid >> 6;
    const int wr = w >> 1, wc = w & 1;
    const int lrow = lane & 15, lkg = lane >> 4;

    f32x4 acc[4][4];
#pragma unroll
    for (int i = 0; i < 4; i++)
#pragma unroll
        for (int j = 0; j < 4; j++) acc[i][j] = (f32x4)0.0f;

    for (int k0 = 0; k0 < 2048; k0 += 64) {
        stage128x64(Abase + k0, 2048, a_lds, tid);
        stage128x64(Bbase + k0, 2048, b_lds, tid);
        __syncthreads();
        mfma_tile(a_lds, b_lds, acc, wr, wc, lrow, lkg);
        __syncthreads();
    }

#pragma unroll
    for (int mi = 0; mi < 4; mi++) {
        const int nbase = nb * 128 + wr * 64 + mi * 16 + lkg * 4;
#pragma unroll
        for (int ni = 0; ni < 4; ni++) {
            const int d = db * 128 + wc * 64 + ni * 16 + lrow;
#pragma unroll
            for (int rr = 0; rr < 4; rr++)
                out[((size_t)bg * 2048 + nbase + rr) * 512 + d] = acc[mi][ni][rr];
        }
    }
}

// ---------------------------------------------------------------------------
extern "C" void kernel_launch(void* const* d_in, const int* in_sizes, int n_in,
                              void* d_out, int out_size, void* d_ws, size_t ws_size,
                              hipStream_t stream) {
    const float* x  = (const float*)d_in[0];
    const float* Wq = (const float*)d_in[1];
    const float* Wk = (const float*)d_in[2];
    const float* Wv = (const float*)d_in[3];

    const size_t MB = 1024ull * 1024ull;
    char* ws = (char*)d_ws;
    _Float16* Qf = (_Float16*)ws;                                  // 16 MB
    _Float16* Kf = Qf + (size_t)16384 * 512;                       // 16 MB
    _Float16* Vt = Kf + (size_t)16384 * 512;                       // 16 MB
    float*    S  = (float*)(Vt + (size_t)16384 * 512);             // chunk * 16 MB
    float*    out = (float*)d_out;

    int chunk;
    if      (ws_size >= 242 * MB) chunk = 8;
    else if (ws_size >= 146 * MB) chunk = 4;
    else if (ws_size >= 98  * MB) chunk = 2;
    else                          chunk = 1;

    _Float16* A = (_Float16*)(S + (size_t)chunk * 2048 * 2048);    // chunk * 8 MB

    // Aliases into regions that are dead until after proj_kernel:
    _Float16* xh = (_Float16*)S;   // 16 MB (S >= 16 MB always; S written after proj)
    _Float16* Wt = (_Float16*)A;   // 1.5 MB (A >= 8 MB; A written after proj)

    convert_kernel<<<2816, 256, 0, stream>>>(x, Wq, Wk, Wv, xh, Wt);
    proj_kernel<<<dim3(12, 128), 256, 0, stream>>>(xh, Wt, Qf, Kf, Vt);

    for (int b0 = 0; b0 < 8; b0 += chunk) {
        score_kernel<<<dim3(16, 16, chunk), 256, 0, stream>>>(Qf, Kf, S, b0);
        softmax_kernel<<<chunk * 512, 256, 0, stream>>>(S, A);
        out_kernel<<<dim3(4, 16, chunk), 256, 0, stream>>>(A, Vt, out, b0);
    }
}

// Round 5
// 177.243 us; speedup vs baseline: 1.2855x; 1.0550x over previous
//
#include <hip/hip_runtime.h>
#include <hip/hip_fp16.h>

typedef _Float16 f16x8 __attribute__((ext_vector_type(8)));
typedef _Float16 f16x4 __attribute__((ext_vector_type(4)));
typedef float    f32x4 __attribute__((ext_vector_type(4)));

#define LOG2E 1.44269504f

// ---------------------------------------------------------------------------
// Staging: 128 rows x 64 halves fp16 tile -> 16 KB linear LDS via
// global_load_lds dwordx4. Source col pre-swizzled (byte ^= (row&7)<<4);
// readers apply the same XOR (rule #21).
// ---------------------------------------------------------------------------
__device__ __forceinline__ void stage128x64(const _Float16* __restrict__ g, int ld,
                                            void* lds, int tid)
{
    const int r0   = tid >> 3;
    const int colh = ((tid & 7) ^ (r0 & 7)) << 3;
    char* lbase = (char*)lds + (tid >> 6) * 1024;
#pragma unroll
    for (int i = 0; i < 4; i++) {
        const _Float16* src = g + (size_t)(i * 32 + r0) * ld + colh;
        __builtin_amdgcn_global_load_lds(
            (const __attribute__((address_space(1))) void*)src,
            (__attribute__((address_space(3))) void*)(lbase + i * 4096),
            16, 0, 0);
    }
}

__device__ __forceinline__ f16x8 lds_frag(const void* lds, int row, int colh)
{
    const int off = row * 128 + ((colh * 2) ^ ((row & 7) << 4));
    return *(const f16x8*)((const char*)lds + off);
}

__device__ __forceinline__ void mfma_tile(const void* a_lds, const void* b_lds,
                                          f32x4 acc[4][4],
                                          int wr, int wc, int lrow, int lkg)
{
#pragma unroll
    for (int kk = 0; kk < 2; kk++) {
        f16x8 af[4], bf[4];
#pragma unroll
        for (int mi = 0; mi < 4; mi++)
            af[mi] = lds_frag(a_lds, wr * 64 + mi * 16 + lrow, kk * 32 + lkg * 8);
#pragma unroll
        for (int ni = 0; ni < 4; ni++)
            bf[ni] = lds_frag(b_lds, wc * 64 + ni * 16 + lrow, kk * 32 + lkg * 8);
#pragma unroll
        for (int mi = 0; mi < 4; mi++)
#pragma unroll
            for (int ni = 0; ni < 4; ni++)
                acc[mi][ni] = __builtin_amdgcn_mfma_f32_16x16x32_f16(af[mi], bf[ni], acc[mi][ni], 0, 0, 0);
    }
}

// ---------------------------------------------------------------------------
// Kernel 0: convert x -> fp16 xh; W{q,k,v} -> fp16 transposed Wt[3][n][k].
// ---------------------------------------------------------------------------
__global__ __launch_bounds__(256)
void convert_kernel(const float* __restrict__ x,
                    const float* __restrict__ Wq,
                    const float* __restrict__ Wk,
                    const float* __restrict__ Wv,
                    _Float16* __restrict__ xh,
                    _Float16* __restrict__ Wt)
{
    const int b = blockIdx.x;
    if (b < 2048) {
        const size_t base = (size_t)b * 4096 + (size_t)threadIdx.x * 4;
#pragma unroll
        for (int i = 0; i < 4; i++) {
            f32x4 v = *(const f32x4*)(x + base + i * 1024);
            f16x4 h;
#pragma unroll
            for (int j = 0; j < 4; j++) h[j] = (_Float16)v[j];
            *(f16x4*)(xh + base + i * 1024) = h;
        }
    } else {
        __shared__ float tb[32][33];
        const int t = b - 2048;
        const int mat = t >> 8;
        const int tile = t & 255;
        const int tr = tile >> 4, tc = tile & 15;
        const float* W = (mat == 0) ? Wq : (mat == 1) ? Wk : Wv;
        const int r = threadIdx.x >> 5, c = threadIdx.x & 31;
#pragma unroll
        for (int p = 0; p < 4; p++)
            tb[p * 8 + r][c] = W[(size_t)(tr * 32 + p * 8 + r) * 512 + tc * 32 + c];
        __syncthreads();
#pragma unroll
        for (int p = 0; p < 4; p++)
            Wt[((size_t)mat * 512 + tc * 32 + p * 8 + r) * 512 + tr * 32 + c] =
                (_Float16)tb[c][p * 8 + r];
    }
}

// ---------------------------------------------------------------------------
// Kernel 1: QKV projection (all-fp16). Q,K row-major; V transposed [b][d][m].
// ---------------------------------------------------------------------------
__global__ __launch_bounds__(256)
void proj_kernel(const _Float16* __restrict__ xh,
                 const _Float16* __restrict__ Wt,
                 _Float16* __restrict__ Qf,
                 _Float16* __restrict__ Kf,
                 _Float16* __restrict__ Vt)
{
    __shared__ _Float16 a_lds[128 * 64];
    __shared__ _Float16 b_lds[128 * 64];

    const int tid = threadIdx.x;
    const int cb = blockIdx.x, mb = blockIdx.y;
    const int mat = cb >> 2, nb = cb & 3;
    const int m0 = mb * 128, n0 = nb * 128;

    const _Float16* Abase = xh + (size_t)m0 * 512;
    const _Float16* Bbase = Wt + ((size_t)mat * 512 + n0) * 512;

    const int lane = tid & 63;
    const int w = tid >> 6;
    const int wr = w >> 1, wc = w & 1;
    const int lrow = lane & 15, lkg = lane >> 4;

    f32x4 acc[4][4];
#pragma unroll
    for (int i = 0; i < 4; i++)
#pragma unroll
        for (int j = 0; j < 4; j++) acc[i][j] = (f32x4)0.0f;

    for (int k0 = 0; k0 < 512; k0 += 64) {
        stage128x64(Abase + k0, 512, a_lds, tid);
        stage128x64(Bbase + k0, 512, b_lds, tid);
        __syncthreads();
        mfma_tile(a_lds, b_lds, acc, wr, wc, lrow, lkg);
        __syncthreads();
    }

    if (mat < 2) {
        _Float16* Out = (mat == 0) ? Qf : Kf;
#pragma unroll
        for (int mi = 0; mi < 4; mi++) {
            const int mbase = m0 + wr * 64 + mi * 16 + lkg * 4;
#pragma unroll
            for (int ni = 0; ni < 4; ni++) {
                const int ncol = n0 + wc * 64 + ni * 16 + lrow;
#pragma unroll
                for (int r = 0; r < 4; r++)
                    Out[(size_t)(mbase + r) * 512 + ncol] = (_Float16)acc[mi][ni][r];
            }
        }
    } else {
#pragma unroll
        for (int mi = 0; mi < 4; mi++) {
            const int mglob = m0 + wr * 64 + mi * 16 + lkg * 4;
            const int b = mglob >> 11, mloc = mglob & 2047;
#pragma unroll
            for (int ni = 0; ni < 4; ni++) {
                const int d = n0 + wc * 64 + ni * 16 + lrow;
                f16x4 h;
#pragma unroll
                for (int r = 0; r < 4; r++) h[r] = (_Float16)acc[mi][ni][r];
                *(f16x4*)&Vt[((size_t)b * 512 + d) * 2048 + mloc] = h;
            }
        }
    }
}

// ---------------------------------------------------------------------------
// Kernel 2: S-tile = Q @ K^T + tile-local softmax stats.
// Writes P = exp(S - m_tile) fp16 [bl][row][key], ML = (m_tile, l_tile)
// float2 [bl][row][16 ktiles]. grid (mb=ktile 16, nb=qtile 16, chunk).
// ---------------------------------------------------------------------------
__global__ __launch_bounds__(256)
void score_kernel(const _Float16* __restrict__ Qf,
                  const _Float16* __restrict__ Kf,
                  _Float16* __restrict__ P,
                  float2* __restrict__ ML, int b0)
{
    __shared__ _Float16 a_lds[128 * 64];
    __shared__ _Float16 b_lds[128 * 64];
    __shared__ float redm[2][128];
    __shared__ float reds[2][128];

    const int tid = threadIdx.x;
    const int mb = blockIdx.x, nb = blockIdx.y, bl = blockIdx.z;
    const int bg = b0 + bl;

    const _Float16* Abase = Qf + (size_t)(bg * 2048 + nb * 128) * 512;
    const _Float16* Bbase = Kf + (size_t)(bg * 2048 + mb * 128) * 512;

    const int lane = tid & 63;
    const int w = tid >> 6;
    const int wr = w >> 1, wc = w & 1;
    const int lrow = lane & 15, lkg = lane >> 4;

    f32x4 acc[4][4];
#pragma unroll
    for (int i = 0; i < 4; i++)
#pragma unroll
        for (int j = 0; j < 4; j++) acc[i][j] = (f32x4)0.0f;

    for (int k0 = 0; k0 < 512; k0 += 64) {
        stage128x64(Abase + k0, 512, a_lds, tid);
        stage128x64(Bbase + k0, 512, b_lds, tid);
        __syncthreads();
        mfma_tile(a_lds, b_lds, acc, wr, wc, lrow, lkg);
        __syncthreads();
    }

    // ---- tile-local softmax stats. q-row_local = wr*64+mi*16+lkg*4+rr,
    //      key_local = wc*64+ni*16+lrow.
    float mt[4][4], lt[4][4];

    // row max over this wave's 64 keys (4 ni x 16 lrow butterfly)
#pragma unroll
    for (int mi = 0; mi < 4; mi++)
#pragma unroll
        for (int rr = 0; rr < 4; rr++) {
            float v = fmaxf(fmaxf(acc[mi][0][rr], acc[mi][1][rr]),
                            fmaxf(acc[mi][2][rr], acc[mi][3][rr]));
#pragma unroll
            for (int off = 1; off < 16; off <<= 1) v = fmaxf(v, __shfl_xor(v, off));
            mt[mi][rr] = v;
        }
    // exchange with the other wc-half
#pragma unroll
    for (int mi = 0; mi < 4; mi++)
#pragma unroll
        for (int rr = 0; rr < 4; rr++)
            if (lrow == 0) redm[wc][wr * 64 + mi * 16 + lkg * 4 + rr] = mt[mi][rr];
    __syncthreads();
#pragma unroll
    for (int mi = 0; mi < 4; mi++)
#pragma unroll
        for (int rr = 0; rr < 4; rr++)
            mt[mi][rr] = fmaxf(mt[mi][rr], redm[wc ^ 1][wr * 64 + mi * 16 + lkg * 4 + rr]);

    // p = exp(s - m_t), row sums
#pragma unroll
    for (int mi = 0; mi < 4; mi++)
#pragma unroll
        for (int rr = 0; rr < 4; rr++) {
            float s = 0.0f;
#pragma unroll
            for (int ni = 0; ni < 4; ni++) {
                float p = exp2f((acc[mi][ni][rr] - mt[mi][rr]) * LOG2E);
                acc[mi][ni][rr] = p;
                s += p;
            }
#pragma unroll
            for (int off = 1; off < 16; off <<= 1) s += __shfl_xor(s, off);
            lt[mi][rr] = s;
        }
#pragma unroll
    for (int mi = 0; mi < 4; mi++)
#pragma unroll
        for (int rr = 0; rr < 4; rr++)
            if (lrow == 0) reds[wc][wr * 64 + mi * 16 + lkg * 4 + rr] = lt[mi][rr];
    __syncthreads();
#pragma unroll
    for (int mi = 0; mi < 4; mi++)
#pragma unroll
        for (int rr = 0; rr < 4; rr++)
            lt[mi][rr] += reds[wc ^ 1][wr * 64 + mi * 16 + lkg * 4 + rr];

    // write ML (one lane per row)
    if (wc == 0 && lrow == 0) {
#pragma unroll
        for (int mi = 0; mi < 4; mi++)
#pragma unroll
            for (int rr = 0; rr < 4; rr++) {
                const int row = nb * 128 + wr * 64 + mi * 16 + lkg * 4 + rr;
                float2 v; v.x = mt[mi][rr]; v.y = lt[mi][rr];
                ML[((size_t)bl * 2048 + row) * 16 + mb] = v;
            }
    }

    // write P fp16
    _Float16* Pb = P + (size_t)bl * 2048 * 2048;
#pragma unroll
    for (int mi = 0; mi < 4; mi++) {
        const int rbase = nb * 128 + wr * 64 + mi * 16 + lkg * 4;
#pragma unroll
        for (int ni = 0; ni < 4; ni++) {
            const int key = mb * 128 + wc * 64 + ni * 16 + lrow;
#pragma unroll
            for (int rr = 0; rr < 4; rr++)
                Pb[(size_t)(rbase + rr) * 2048 + key] = (_Float16)acc[mi][ni][rr];
        }
    }
}

// ---------------------------------------------------------------------------
// Kernel 4: out = scaled-P @ V. Prologue builds scale[row][ktile] =
// exp(m_t - M)/L from ML; A-fragments multiplied by fp16 scale per ktile.
// grid (db 4, nb 16, chunk). Output fp32 [b][2048][512].
// ---------------------------------------------------------------------------
__global__ __launch_bounds__(256)
void out_kernel(const _Float16* __restrict__ P,
                const _Float16* __restrict__ Vt,
                const float2* __restrict__ ML,
                float* __restrict__ out, int b0)
{
    __shared__ _Float16 a_lds[128 * 64];
    __shared__ _Float16 b_lds[128 * 64];
    __shared__ float scale_lds[128][17];

    const int tid = threadIdx.x;
    const int db = blockIdx.x, nb = blockIdx.y, bl = blockIdx.z;
    const int bg = b0 + bl;

    // prologue: per-row global stats from 16 tile stats
    if (tid < 128) {
        const float2* mlrow = ML + ((size_t)bl * 2048 + nb * 128 + tid) * 16;
        float2 ml[16];
        float M = -3.4e38f;
#pragma unroll
        for (int t = 0; t < 16; t++) { ml[t] = mlrow[t]; M = fmaxf(M, ml[t].x); }
        float L = 0.0f;
#pragma unroll
        for (int t = 0; t < 16; t++) L += ml[t].y * exp2f((ml[t].x - M) * LOG2E);
        const float invL = 1.0f / L;
#pragma unroll
        for (int t = 0; t < 16; t++)
            scale_lds[tid][t] = exp2f((ml[t].x - M) * LOG2E) * invL;
    }

    const _Float16* Abase = P  + (size_t)bl * 2048 * 2048 + (size_t)(nb * 128) * 2048;
    const _Float16* Bbase = Vt + (size_t)bg * 512  * 2048 + (size_t)(db * 128) * 2048;

    const int lane = tid & 63;
    const int w = tid >> 6;
    const int wr = w >> 1, wc = w & 1;
    const int lrow = lane & 15, lkg = lane >> 4;

    f32x4 acc[4][4];
#pragma unroll
    for (int i = 0; i < 4; i++)
#pragma unroll
        for (int j = 0; j < 4; j++) acc[i][j] = (f32x4)0.0f;

    __syncthreads();   // scale_lds ready before first K-step's ds_reads

    for (int k0 = 0; k0 < 2048; k0 += 64) {
        stage128x64(Abase + k0, 2048, a_lds, tid);
        stage128x64(Bbase + k0, 2048, b_lds, tid);
        __syncthreads();
        const int kt = k0 >> 7;
#pragma unroll
        for (int kk = 0; kk < 2; kk++) {
            f16x8 af[4], bf[4];
#pragma unroll
            for (int mi = 0; mi < 4; mi++) {
                af[mi] = lds_frag(a_lds, wr * 64 + mi * 16 + lrow, kk * 32 + lkg * 8);
                const _Float16 hs = (_Float16)scale_lds[wr * 64 + mi * 16 + lrow][kt];
                af[mi] *= hs;
            }
#pragma unroll
            for (int ni = 0; ni < 4; ni++)
                bf[ni] = lds_frag(b_lds, wc * 64 + ni * 16 + lrow, kk * 32 + lkg * 8);
#pragma unroll
            for (int mi = 0; mi < 4; mi++)
#pragma unroll
                for (int ni = 0; ni < 4; ni++)
                    acc[mi][ni] = __builtin_amdgcn_mfma_f32_16x16x32_f16(af[mi], bf[ni], acc[mi][ni], 0, 0, 0);
        }
        __syncthreads();
    }

#pragma unroll
    for (int mi = 0; mi < 4; mi++) {
        const int nbase = nb * 128 + wr * 64 + mi * 16 + lkg * 4;
#pragma unroll
        for (int ni = 0; ni < 4; ni++) {
            const int d = db * 128 + wc * 64 + ni * 16 + lrow;
#pragma unroll
            for (int rr = 0; rr < 4; rr++)
                out[((size_t)bg * 2048 + nbase + rr) * 512 + d] = acc[mi][ni][rr];
        }
    }
}

// ---------------------------------------------------------------------------
extern "C" void kernel_launch(void* const* d_in, const int* in_sizes, int n_in,
                              void* d_out, int out_size, void* d_ws, size_t ws_size,
                              hipStream_t stream) {
    const float* x  = (const float*)d_in[0];
    const float* Wq = (const float*)d_in[1];
    const float* Wk = (const float*)d_in[2];
    const float* Wv = (const float*)d_in[3];

    const size_t MB = 1024ull * 1024ull;
    char* ws = (char*)d_ws;
    _Float16* Qf = (_Float16*)ws;                                  // 16 MB
    _Float16* Kf = Qf + (size_t)16384 * 512;                       // 16 MB
    _Float16* Vt = Kf + (size_t)16384 * 512;                       // 16 MB
    _Float16* P  = Vt + (size_t)16384 * 512;                       // chunk * 8 MB
    float*    out = (float*)d_out;

    int chunk;
    if      (ws_size >= 120 * MB) chunk = 8;
    else if (ws_size >= 88  * MB) chunk = 4;
    else if (ws_size >= 70  * MB) chunk = 2;
    else                          chunk = 1;

    float2* ML = (float2*)(P + (size_t)chunk * 2048 * 2048);       // chunk * 256 KB

    // Aliases into the P/ML region (dead until score_kernel runs):
    _Float16* xh = (_Float16*)P;                    // 16 MB
    _Float16* Wt = xh + (size_t)16384 * 512;        // 1.5 MB  (needs ws >= 65.5 MB)

    convert_kernel<<<2816, 256, 0, stream>>>(x, Wq, Wk, Wv, xh, Wt);
    proj_kernel<<<dim3(12, 128), 256, 0, stream>>>(xh, Wt, Qf, Kf, Vt);

    for (int b0 = 0; b0 < 8; b0 += chunk) {
        score_kernel<<<dim3(16, 16, chunk), 256, 0, stream>>>(Qf, Kf, P, ML, b0);
        out_kernel<<<dim3(4, 16, chunk), 256, 0, stream>>>(P, Vt, ML, out, b0);
    }
}

// Round 6
// 166.447 us; speedup vs baseline: 1.3688x; 1.0649x over previous
//
#include <hip/hip_runtime.h>
#include <hip/hip_fp16.h>

typedef _Float16 f16x8 __attribute__((ext_vector_type(8)));
typedef _Float16 f16x4 __attribute__((ext_vector_type(4)));
typedef float    f32x4 __attribute__((ext_vector_type(4)));

#define LOG2E 1.44269504f

// ---------------------------------------------------------------------------
// Staging: 128 rows x 64 halves fp16 tile -> 16 KB linear LDS via
// global_load_lds dwordx4. Source col pre-swizzled (byte ^= (row&7)<<4);
// readers apply the same XOR (rule #21).
// ---------------------------------------------------------------------------
__device__ __forceinline__ void stage128x64(const _Float16* __restrict__ g, int ld,
                                            void* lds, int tid)
{
    const int r0   = tid >> 3;
    const int colh = ((tid & 7) ^ (r0 & 7)) << 3;
    char* lbase = (char*)lds + (tid >> 6) * 1024;
#pragma unroll
    for (int i = 0; i < 4; i++) {
        const _Float16* src = g + (size_t)(i * 32 + r0) * ld + colh;
        __builtin_amdgcn_global_load_lds(
            (const __attribute__((address_space(1))) void*)src,
            (__attribute__((address_space(3))) void*)(lbase + i * 4096),
            16, 0, 0);
    }
}

__device__ __forceinline__ f16x8 lds_frag(const void* lds, int row, int colh)
{
    const int off = row * 128 + ((colh * 2) ^ ((row & 7) << 4));
    return *(const f16x8*)((const char*)lds + off);
}

__device__ __forceinline__ void mfma_tile(const void* a_lds, const void* b_lds,
                                          f32x4 acc[4][4],
                                          int wr, int wc, int lrow, int lkg)
{
#pragma unroll
    for (int kk = 0; kk < 2; kk++) {
        f16x8 af[4], bf[4];
#pragma unroll
        for (int mi = 0; mi < 4; mi++)
            af[mi] = lds_frag(a_lds, wr * 64 + mi * 16 + lrow, kk * 32 + lkg * 8);
#pragma unroll
        for (int ni = 0; ni < 4; ni++)
            bf[ni] = lds_frag(b_lds, wc * 64 + ni * 16 + lrow, kk * 32 + lkg * 8);
#pragma unroll
        for (int mi = 0; mi < 4; mi++)
#pragma unroll
            for (int ni = 0; ni < 4; ni++)
                acc[mi][ni] = __builtin_amdgcn_mfma_f32_16x16x32_f16(af[mi], bf[ni], acc[mi][ni], 0, 0, 0);
    }
}

// ---------------------------------------------------------------------------
// Kernel 0: convert x -> fp16 xh; W{q,k,v} -> fp16 transposed Wt[3][n][k].
// ---------------------------------------------------------------------------
__global__ __launch_bounds__(256)
void convert_kernel(const float* __restrict__ x,
                    const float* __restrict__ Wq,
                    const float* __restrict__ Wk,
                    const float* __restrict__ Wv,
                    _Float16* __restrict__ xh,
                    _Float16* __restrict__ Wt)
{
    const int b = blockIdx.x;
    if (b < 2048) {
        const size_t base = (size_t)b * 4096 + (size_t)threadIdx.x * 4;
#pragma unroll
        for (int i = 0; i < 4; i++) {
            f32x4 v = *(const f32x4*)(x + base + i * 1024);
            f16x4 h;
#pragma unroll
            for (int j = 0; j < 4; j++) h[j] = (_Float16)v[j];
            *(f16x4*)(xh + base + i * 1024) = h;
        }
    } else {
        __shared__ float tb[32][33];
        const int t = b - 2048;
        const int mat = t >> 8;
        const int tile = t & 255;
        const int tr = tile >> 4, tc = tile & 15;
        const float* W = (mat == 0) ? Wq : (mat == 1) ? Wk : Wv;
        const int r = threadIdx.x >> 5, c = threadIdx.x & 31;
#pragma unroll
        for (int p = 0; p < 4; p++)
            tb[p * 8 + r][c] = W[(size_t)(tr * 32 + p * 8 + r) * 512 + tc * 32 + c];
        __syncthreads();
#pragma unroll
        for (int p = 0; p < 4; p++)
            Wt[((size_t)mat * 512 + tc * 32 + p * 8 + r) * 512 + tr * 32 + c] =
                (_Float16)tb[c][p * 8 + r];
    }
}

// ---------------------------------------------------------------------------
// Kernel 1: QKV projection (all-fp16). Q,K row-major; V transposed [b][d][m].
// ---------------------------------------------------------------------------
__global__ __launch_bounds__(256)
void proj_kernel(const _Float16* __restrict__ xh,
                 const _Float16* __restrict__ Wt,
                 _Float16* __restrict__ Qf,
                 _Float16* __restrict__ Kf,
                 _Float16* __restrict__ Vt)
{
    __shared__ _Float16 a_lds[128 * 64];
    __shared__ _Float16 b_lds[128 * 64];

    const int tid = threadIdx.x;
    const int cb = blockIdx.x, mb = blockIdx.y;
    const int mat = cb >> 2, nb = cb & 3;
    const int m0 = mb * 128, n0 = nb * 128;

    const _Float16* Abase = xh + (size_t)m0 * 512;
    const _Float16* Bbase = Wt + ((size_t)mat * 512 + n0) * 512;

    const int lane = tid & 63;
    const int w = tid >> 6;
    const int wr = w >> 1, wc = w & 1;
    const int lrow = lane & 15, lkg = lane >> 4;

    f32x4 acc[4][4];
#pragma unroll
    for (int i = 0; i < 4; i++)
#pragma unroll
        for (int j = 0; j < 4; j++) acc[i][j] = (f32x4)0.0f;

    for (int k0 = 0; k0 < 512; k0 += 64) {
        stage128x64(Abase + k0, 512, a_lds, tid);
        stage128x64(Bbase + k0, 512, b_lds, tid);
        __syncthreads();
        mfma_tile(a_lds, b_lds, acc, wr, wc, lrow, lkg);
        __syncthreads();
    }

    if (mat < 2) {
        _Float16* Out = (mat == 0) ? Qf : Kf;
#pragma unroll
        for (int mi = 0; mi < 4; mi++) {
            const int mbase = m0 + wr * 64 + mi * 16 + lkg * 4;
#pragma unroll
            for (int ni = 0; ni < 4; ni++) {
                const int ncol = n0 + wc * 64 + ni * 16 + lrow;
#pragma unroll
                for (int r = 0; r < 4; r++)
                    Out[(size_t)(mbase + r) * 512 + ncol] = (_Float16)acc[mi][ni][r];
            }
        }
    } else {
#pragma unroll
        for (int mi = 0; mi < 4; mi++) {
            const int mglob = m0 + wr * 64 + mi * 16 + lkg * 4;
            const int b = mglob >> 11, mloc = mglob & 2047;
#pragma unroll
            for (int ni = 0; ni < 4; ni++) {
                const int d = n0 + wc * 64 + ni * 16 + lrow;
                f16x4 h;
#pragma unroll
                for (int r = 0; r < 4; r++) h[r] = (_Float16)acc[mi][ni][r];
                *(f16x4*)&Vt[((size_t)b * 512 + d) * 2048 + mloc] = h;
            }
        }
    }
}

// ---------------------------------------------------------------------------
// Kernel 2: S-tile = Q @ K^T, tile-local softmax via LDS-transpose epilogue.
// Writes P = exp(S - m_tile) fp16 (coalesced dwordx4), ML=(m_t,l_t) float2.
// S_lds (fp32 [64][132], 33 KB) is UNION'd over a_lds/b_lds (dead after loop).
// grid (mb=ktile 16, nb=qtile 16, chunk).
// ---------------------------------------------------------------------------
__global__ __launch_bounds__(256)
void score_kernel(const _Float16* __restrict__ Qf,
                  const _Float16* __restrict__ Kf,
                  _Float16* __restrict__ P,
                  float2* __restrict__ ML, int b0)
{
    __shared__ __align__(16) char smem[64 * 132 * 4];   // 33792 B
    _Float16* a_lds = (_Float16*)smem;                  // 16 KB
    _Float16* b_lds = (_Float16*)(smem + 16384);        // 16 KB
    float (*S_lds)[132] = (float(*)[132])smem;          // overlaps a+b

    const int tid = threadIdx.x;
    const int mb = blockIdx.x, nb = blockIdx.y, bl = blockIdx.z;
    const int bg = b0 + bl;

    const _Float16* Abase = Qf + (size_t)(bg * 2048 + nb * 128) * 512;
    const _Float16* Bbase = Kf + (size_t)(bg * 2048 + mb * 128) * 512;

    const int lane = tid & 63;
    const int w = tid >> 6;
    const int wr = w >> 1, wc = w & 1;
    const int lrow = lane & 15, lkg = lane >> 4;

    f32x4 acc[4][4];
#pragma unroll
    for (int i = 0; i < 4; i++)
#pragma unroll
        for (int j = 0; j < 4; j++) acc[i][j] = (f32x4)0.0f;

    for (int k0 = 0; k0 < 512; k0 += 64) {
        stage128x64(Abase + k0, 512, a_lds, tid);
        stage128x64(Bbase + k0, 512, b_lds, tid);
        __syncthreads();
        mfma_tile(a_lds, b_lds, acc, wr, wc, lrow, lkg);
        __syncthreads();
    }
    // trailing syncthreads above: all waves' LDS reads done -> S_lds reuse safe

    _Float16* Pb = P + (size_t)bl * 2048 * 2048;
    const int s  = tid >> 2;          // 0..63: S_lds row this thread reduces
    const int c0 = (tid & 3) * 32;    // col span start

#pragma unroll
    for (int hp = 0; hp < 2; hp++) {
        // ---- scatter this half's acc quadrants into S_lds ----
#pragma unroll
        for (int m2 = 0; m2 < 2; m2++) {
            const int mi = hp * 2 + m2;
            const int srow = wr * 32 + m2 * 16 + lkg * 4;
#pragma unroll
            for (int ni = 0; ni < 4; ni++) {
                const int col = wc * 64 + ni * 16 + lrow;
#pragma unroll
                for (int rr = 0; rr < 4; rr++)
                    S_lds[srow + rr][col] = acc[mi][ni][rr];
            }
        }
        __syncthreads();

        // ---- row-contiguous re-read: 4 threads per row, 32 cols each ----
        f32x4 vv[8];
#pragma unroll
        for (int j = 0; j < 8; j++)
            vv[j] = *(const f32x4*)&S_lds[s][c0 + j * 4];

        float m = vv[0][0];
#pragma unroll
        for (int j = 0; j < 8; j++)
#pragma unroll
            for (int jj = 0; jj < 4; jj++) m = fmaxf(m, vv[j][jj]);
        m = fmaxf(m, __shfl_xor(m, 1));
        m = fmaxf(m, __shfl_xor(m, 2));

        float l = 0.0f;
#pragma unroll
        for (int j = 0; j < 8; j++)
#pragma unroll
            for (int jj = 0; jj < 4; jj++) {
                float e = exp2f((vv[j][jj] - m) * LOG2E);
                vv[j][jj] = e;
                l += e;
            }
        l += __shfl_xor(l, 1);
        l += __shfl_xor(l, 2);

        const int q_local = (s >> 5) * 64 + hp * 32 + (s & 31);
        const int q = nb * 128 + q_local;

        if ((tid & 3) == 0) {
            float2 v; v.x = m; v.y = l;
            ML[((size_t)bl * 2048 + q) * 16 + mb] = v;
        }

        // ---- pack fp16, coalesced dwordx4 stores ----
#pragma unroll
        for (int j = 0; j < 4; j++) {
            f16x8 h;
#pragma unroll
            for (int jj = 0; jj < 8; jj++) {
                const int idx = j * 8 + jj;
                h[jj] = (_Float16)vv[idx >> 2][idx & 3];
            }
            *(f16x8*)&Pb[(size_t)q * 2048 + mb * 128 + c0 + j * 8] = h;
        }
        __syncthreads();   // S_lds reads done before next half overwrites
    }
}

// ---------------------------------------------------------------------------
// Kernel 4: out = scaled-P @ V. Prologue builds scale[row][ktile] =
// exp(m_t - M)/L from ML; A-fragments multiplied by fp16 scale per ktile.
// grid (db 4, nb 16, chunk). Output fp32 [b][2048][512].
// ---------------------------------------------------------------------------
__global__ __launch_bounds__(256)
void out_kernel(const _Float16* __restrict__ P,
                const _Float16* __restrict__ Vt,
                const float2* __restrict__ ML,
                float* __restrict__ out, int b0)
{
    __shared__ _Float16 a_lds[128 * 64];
    __shared__ _Float16 b_lds[128 * 64];
    __shared__ float scale_lds[128][17];

    const int tid = threadIdx.x;
    const int db = blockIdx.x, nb = blockIdx.y, bl = blockIdx.z;
    const int bg = b0 + bl;

    if (tid < 128) {
        const float2* mlrow = ML + ((size_t)bl * 2048 + nb * 128 + tid) * 16;
        float2 ml[16];
        float M = -3.4e38f;
#pragma unroll
        for (int t = 0; t < 16; t++) { ml[t] = mlrow[t]; M = fmaxf(M, ml[t].x); }
        float L = 0.0f;
#pragma unroll
        for (int t = 0; t < 16; t++) L += ml[t].y * exp2f((ml[t].x - M) * LOG2E);
        const float invL = 1.0f / L;
#pragma unroll
        for (int t = 0; t < 16; t++)
            scale_lds[tid][t] = exp2f((ml[t].x - M) * LOG2E) * invL;
    }

    const _Float16* Abase = P  + (size_t)bl * 2048 * 2048 + (size_t)(nb * 128) * 2048;
    const _Float16* Bbase = Vt + (size_t)bg * 512  * 2048 + (size_t)(db * 128) * 2048;

    const int lane = tid & 63;
    const int w = tid >> 6;
    const int wr = w >> 1, wc = w & 1;
    const int lrow = lane & 15, lkg = lane >> 4;

    f32x4 acc[4][4];
#pragma unroll
    for (int i = 0; i < 4; i++)
#pragma unroll
        for (int j = 0; j < 4; j++) acc[i][j] = (f32x4)0.0f;

    __syncthreads();

    for (int k0 = 0; k0 < 2048; k0 += 64) {
        stage128x64(Abase + k0, 2048, a_lds, tid);
        stage128x64(Bbase + k0, 2048, b_lds, tid);
        __syncthreads();
        const int kt = k0 >> 7;
#pragma unroll
        for (int kk = 0; kk < 2; kk++) {
            f16x8 af[4], bf[4];
#pragma unroll
            for (int mi = 0; mi < 4; mi++) {
                af[mi] = lds_frag(a_lds, wr * 64 + mi * 16 + lrow, kk * 32 + lkg * 8);
                const _Float16 hs = (_Float16)scale_lds[wr * 64 + mi * 16 + lrow][kt];
                af[mi] *= hs;
            }
#pragma unroll
            for (int ni = 0; ni < 4; ni++)
                bf[ni] = lds_frag(b_lds, wc * 64 + ni * 16 + lrow, kk * 32 + lkg * 8);
#pragma unroll
            for (int mi = 0; mi < 4; mi++)
#pragma unroll
                for (int ni = 0; ni < 4; ni++)
                    acc[mi][ni] = __builtin_amdgcn_mfma_f32_16x16x32_f16(af[mi], bf[ni], acc[mi][ni], 0, 0, 0);
        }
        __syncthreads();
    }

#pragma unroll
    for (int mi = 0; mi < 4; mi++) {
        const int nbase = nb * 128 + wr * 64 + mi * 16 + lkg * 4;
#pragma unroll
        for (int ni = 0; ni < 4; ni++) {
            const int d = db * 128 + wc * 64 + ni * 16 + lrow;
#pragma unroll
            for (int rr = 0; rr < 4; rr++)
                out[((size_t)bg * 2048 + nbase + rr) * 512 + d] = acc[mi][ni][rr];
        }
    }
}

// ---------------------------------------------------------------------------
extern "C" void kernel_launch(void* const* d_in, const int* in_sizes, int n_in,
                              void* d_out, int out_size, void* d_ws, size_t ws_size,
                              hipStream_t stream) {
    const float* x  = (const float*)d_in[0];
    const float* Wq = (const float*)d_in[1];
    const float* Wk = (const float*)d_in[2];
    const float* Wv = (const float*)d_in[3];

    const size_t MB = 1024ull * 1024ull;
    char* ws = (char*)d_ws;
    _Float16* Qf = (_Float16*)ws;                                  // 16 MB
    _Float16* Kf = Qf + (size_t)16384 * 512;                       // 16 MB
    _Float16* Vt = Kf + (size_t)16384 * 512;                       // 16 MB
    _Float16* P  = Vt + (size_t)16384 * 512;                       // chunk * 8 MB
    float*    out = (float*)d_out;

    int chunk;
    if      (ws_size >= 120 * MB) chunk = 8;
    else if (ws_size >= 88  * MB) chunk = 4;
    else if (ws_size >= 70  * MB) chunk = 2;
    else                          chunk = 1;

    float2* ML = (float2*)(P + (size_t)chunk * 2048 * 2048);       // chunk * 256 KB

    // Aliases into the P/ML region (dead until score_kernel runs):
    _Float16* xh = (_Float16*)P;                    // 16 MB
    _Float16* Wt = xh + (size_t)16384 * 512;        // 1.5 MB  (needs ws >= 65.5 MB)

    convert_kernel<<<2816, 256, 0, stream>>>(x, Wq, Wk, Wv, xh, Wt);
    proj_kernel<<<dim3(12, 128), 256, 0, stream>>>(xh, Wt, Qf, Kf, Vt);

    for (int b0 = 0; b0 < 8; b0 += chunk) {
        score_kernel<<<dim3(16, 16, chunk), 256, 0, stream>>>(Qf, Kf, P, ML, b0);
        out_kernel<<<dim3(4, 16, chunk), 256, 0, stream>>>(P, Vt, ML, out, b0);
    }
}

// Round 7
// 159.219 us; speedup vs baseline: 1.4310x; 1.0454x over previous
//
#include <hip/hip_runtime.h>
#include <hip/hip_fp16.h>

typedef _Float16 f16x8 __attribute__((ext_vector_type(8)));
typedef _Float16 f16x4 __attribute__((ext_vector_type(4)));
typedef float    f32x4 __attribute__((ext_vector_type(4)));

#define LOG2E 1.44269504f

// ---------------------------------------------------------------------------
// Staging: 128 rows x 64 halves fp16 tile -> 16 KB linear LDS via
// global_load_lds dwordx4. Source col pre-swizzled (byte ^= (row&7)<<4);
// readers apply the same XOR (rule #21).
// ---------------------------------------------------------------------------
__device__ __forceinline__ void stage128x64(const _Float16* __restrict__ g, int ld,
                                            void* lds, int tid)
{
    const int r0   = tid >> 3;
    const int colh = ((tid & 7) ^ (r0 & 7)) << 3;
    char* lbase = (char*)lds + (tid >> 6) * 1024;
#pragma unroll
    for (int i = 0; i < 4; i++) {
        const _Float16* src = g + (size_t)(i * 32 + r0) * ld + colh;
        __builtin_amdgcn_global_load_lds(
            (const __attribute__((address_space(1))) void*)src,
            (__attribute__((address_space(3))) void*)(lbase + i * 4096),
            16, 0, 0);
    }
}

__device__ __forceinline__ f16x8 lds_frag(const void* lds, int row, int colh)
{
    const int off = row * 128 + ((colh * 2) ^ ((row & 7) << 4));
    return *(const f16x8*)((const char*)lds + off);
}

__device__ __forceinline__ void mfma_tile(const void* a_lds, const void* b_lds,
                                          f32x4 acc[4][4],
                                          int wr, int wc, int lrow, int lkg)
{
#pragma unroll
    for (int kk = 0; kk < 2; kk++) {
        f16x8 af[4], bf[4];
#pragma unroll
        for (int mi = 0; mi < 4; mi++)
            af[mi] = lds_frag(a_lds, wr * 64 + mi * 16 + lrow, kk * 32 + lkg * 8);
#pragma unroll
        for (int ni = 0; ni < 4; ni++)
            bf[ni] = lds_frag(b_lds, wc * 64 + ni * 16 + lrow, kk * 32 + lkg * 8);
#pragma unroll
        for (int mi = 0; mi < 4; mi++)
#pragma unroll
            for (int ni = 0; ni < 4; ni++)
                acc[mi][ni] = __builtin_amdgcn_mfma_f32_16x16x32_f16(af[mi], bf[ni], acc[mi][ni], 0, 0, 0);
    }
}

// T3-minimum 2-phase double-buffered GEMM loop: prefetch tile t+1 while
// computing tile t; ONE __syncthreads per iteration (its vmcnt(0) drain
// covers the prefetch, which had the whole MFMA phase in flight).
__device__ __forceinline__ void gemm_loop_db(const _Float16* __restrict__ A, int lda,
                                             const _Float16* __restrict__ B, int ldb,
                                             int nk,
                                             _Float16* a0, _Float16* a1,
                                             _Float16* b0, _Float16* b1,
                                             f32x4 acc[4][4], int tid,
                                             int wr, int wc, int lrow, int lkg)
{
    stage128x64(A, lda, a0, tid);
    stage128x64(B, ldb, b0, tid);
    __syncthreads();
    for (int t = 0; t < nk; ++t) {
        _Float16* acur = (t & 1) ? a1 : a0;
        _Float16* bcur = (t & 1) ? b1 : b0;
        if (t + 1 < nk) {
            _Float16* anx = (t & 1) ? a0 : a1;
            _Float16* bnx = (t & 1) ? b0 : b1;
            stage128x64(A + (size_t)(t + 1) * 64, lda, anx, tid);
            stage128x64(B + (size_t)(t + 1) * 64, ldb, bnx, tid);
        }
        mfma_tile(acur, bcur, acc, wr, wc, lrow, lkg);
        __syncthreads();
    }
}

// ---------------------------------------------------------------------------
// Kernel 0: convert x -> fp16 xh; W{q,k,v} -> fp16 transposed Wt[3][n][k].
// ---------------------------------------------------------------------------
__global__ __launch_bounds__(256)
void convert_kernel(const float* __restrict__ x,
                    const float* __restrict__ Wq,
                    const float* __restrict__ Wk,
                    const float* __restrict__ Wv,
                    _Float16* __restrict__ xh,
                    _Float16* __restrict__ Wt)
{
    const int b = blockIdx.x;
    if (b < 2048) {
        const size_t base = (size_t)b * 4096 + (size_t)threadIdx.x * 4;
#pragma unroll
        for (int i = 0; i < 4; i++) {
            f32x4 v = *(const f32x4*)(x + base + i * 1024);
            f16x4 h;
#pragma unroll
            for (int j = 0; j < 4; j++) h[j] = (_Float16)v[j];
            *(f16x4*)(xh + base + i * 1024) = h;
        }
    } else {
        __shared__ float tb[32][33];
        const int t = b - 2048;
        const int mat = t >> 8;
        const int tile = t & 255;
        const int tr = tile >> 4, tc = tile & 15;
        const float* W = (mat == 0) ? Wq : (mat == 1) ? Wk : Wv;
        const int r = threadIdx.x >> 5, c = threadIdx.x & 31;
#pragma unroll
        for (int p = 0; p < 4; p++)
            tb[p * 8 + r][c] = W[(size_t)(tr * 32 + p * 8 + r) * 512 + tc * 32 + c];
        __syncthreads();
#pragma unroll
        for (int p = 0; p < 4; p++)
            Wt[((size_t)mat * 512 + tc * 32 + p * 8 + r) * 512 + tr * 32 + c] =
                (_Float16)tb[c][p * 8 + r];
    }
}

// ---------------------------------------------------------------------------
// Kernel 1: QKV projection (all-fp16). Q,K row-major; V transposed [b][d][m].
// grid (mb=128 x, cb=12 y): the 12 cb-siblings sharing an xh panel have
// linear id == mb (mod 8) -> same XCD -> L2-shared A panel.
// ---------------------------------------------------------------------------
__global__ __launch_bounds__(256)
void proj_kernel(const _Float16* __restrict__ xh,
                 const _Float16* __restrict__ Wt,
                 _Float16* __restrict__ Qf,
                 _Float16* __restrict__ Kf,
                 _Float16* __restrict__ Vt)
{
    __shared__ _Float16 a0[128 * 64], a1[128 * 64];
    __shared__ _Float16 b0[128 * 64], b1[128 * 64];

    const int tid = threadIdx.x;
    const int mb = blockIdx.x, cb = blockIdx.y;
    const int mat = cb >> 2, nb = cb & 3;
    const int m0 = mb * 128, n0 = nb * 128;

    const _Float16* Abase = xh + (size_t)m0 * 512;
    const _Float16* Bbase = Wt + ((size_t)mat * 512 + n0) * 512;

    const int lane = tid & 63;
    const int w = tid >> 6;
    const int wr = w >> 1, wc = w & 1;
    const int lrow = lane & 15, lkg = lane >> 4;

    f32x4 acc[4][4];
#pragma unroll
    for (int i = 0; i < 4; i++)
#pragma unroll
        for (int j = 0; j < 4; j++) acc[i][j] = (f32x4)0.0f;

    gemm_loop_db(Abase, 512, Bbase, 512, 8, a0, a1, b0, b1,
                 acc, tid, wr, wc, lrow, lkg);

    if (mat < 2) {
        _Float16* Out = (mat == 0) ? Qf : Kf;
#pragma unroll
        for (int mi = 0; mi < 4; mi++) {
            const int mbase = m0 + wr * 64 + mi * 16 + lkg * 4;
#pragma unroll
            for (int ni = 0; ni < 4; ni++) {
                const int ncol = n0 + wc * 64 + ni * 16 + lrow;
#pragma unroll
                for (int r = 0; r < 4; r++)
                    Out[(size_t)(mbase + r) * 512 + ncol] = (_Float16)acc[mi][ni][r];
            }
        }
    } else {
#pragma unroll
        for (int mi = 0; mi < 4; mi++) {
            const int mglob = m0 + wr * 64 + mi * 16 + lkg * 4;
            const int b = mglob >> 11, mloc = mglob & 2047;
#pragma unroll
            for (int ni = 0; ni < 4; ni++) {
                const int d = n0 + wc * 64 + ni * 16 + lrow;
                f16x4 h;
#pragma unroll
                for (int r = 0; r < 4; r++) h[r] = (_Float16)acc[mi][ni][r];
                *(f16x4*)&Vt[((size_t)b * 512 + d) * 2048 + mloc] = h;
            }
        }
    }
}

// ---------------------------------------------------------------------------
// Kernel 2: S-tile = Q @ K^T, tile-local softmax via LDS-transpose epilogue.
// Double-buffered staging (64 KB); S_lds (33 KB fp32) aliases the buffers
// (dead after the loop's final barrier). grid (mb 16, nb 16, chunk).
// ---------------------------------------------------------------------------
__global__ __launch_bounds__(256)
void score_kernel(const _Float16* __restrict__ Qf,
                  const _Float16* __restrict__ Kf,
                  _Float16* __restrict__ P,
                  float2* __restrict__ ML, int b0)
{
    __shared__ __align__(16) char smem[65536];
    _Float16* a0 = (_Float16*)smem;
    _Float16* a1 = (_Float16*)(smem + 16384);
    _Float16* b0p = (_Float16*)(smem + 32768);
    _Float16* b1p = (_Float16*)(smem + 49152);
    float (*S_lds)[132] = (float(*)[132])smem;     // 33792 B, aliases buffers

    const int tid = threadIdx.x;
    const int mb = blockIdx.x, nb = blockIdx.y, bl = blockIdx.z;
    const int bg = b0 + bl;

    const _Float16* Abase = Qf + (size_t)(bg * 2048 + nb * 128) * 512;
    const _Float16* Bbase = Kf + (size_t)(bg * 2048 + mb * 128) * 512;

    const int lane = tid & 63;
    const int w = tid >> 6;
    const int wr = w >> 1, wc = w & 1;
    const int lrow = lane & 15, lkg = lane >> 4;

    f32x4 acc[4][4];
#pragma unroll
    for (int i = 0; i < 4; i++)
#pragma unroll
        for (int j = 0; j < 4; j++) acc[i][j] = (f32x4)0.0f;

    gemm_loop_db(Abase, 512, Bbase, 512, 8, a0, a1, b0p, b1p,
                 acc, tid, wr, wc, lrow, lkg);
    // loop's final __syncthreads: all LDS reads done -> S_lds reuse safe

    _Float16* Pb = P + (size_t)bl * 2048 * 2048;
    const int s  = tid >> 2;          // 0..63: S_lds row this thread reduces
    const int c0 = (tid & 3) * 32;    // col span start

#pragma unroll
    for (int hp = 0; hp < 2; hp++) {
        // ---- scatter this half's acc quadrants into S_lds ----
#pragma unroll
        for (int m2 = 0; m2 < 2; m2++) {
            const int mi = hp * 2 + m2;
            const int srow = wr * 32 + m2 * 16 + lkg * 4;
#pragma unroll
            for (int ni = 0; ni < 4; ni++) {
                const int col = wc * 64 + ni * 16 + lrow;
#pragma unroll
                for (int rr = 0; rr < 4; rr++)
                    S_lds[srow + rr][col] = acc[mi][ni][rr];
            }
        }
        __syncthreads();

        // ---- row-contiguous re-read: 4 threads per row, 32 cols each ----
        f32x4 vv[8];
#pragma unroll
        for (int j = 0; j < 8; j++)
            vv[j] = *(const f32x4*)&S_lds[s][c0 + j * 4];

        float m = vv[0][0];
#pragma unroll
        for (int j = 0; j < 8; j++)
#pragma unroll
            for (int jj = 0; jj < 4; jj++) m = fmaxf(m, vv[j][jj]);
        m = fmaxf(m, __shfl_xor(m, 1));
        m = fmaxf(m, __shfl_xor(m, 2));

        float l = 0.0f;
#pragma unroll
        for (int j = 0; j < 8; j++)
#pragma unroll
            for (int jj = 0; jj < 4; jj++) {
                float e = exp2f((vv[j][jj] - m) * LOG2E);
                vv[j][jj] = e;
                l += e;
            }
        l += __shfl_xor(l, 1);
        l += __shfl_xor(l, 2);

        const int q_local = (s >> 5) * 64 + hp * 32 + (s & 31);
        const int q = nb * 128 + q_local;

        if ((tid & 3) == 0) {
            float2 v; v.x = m; v.y = l;
            ML[((size_t)bl * 2048 + q) * 16 + mb] = v;
        }

        // ---- pack fp16, coalesced dwordx4 stores ----
#pragma unroll
        for (int j = 0; j < 4; j++) {
            f16x8 h;
#pragma unroll
            for (int jj = 0; jj < 8; jj++) {
                const int idx = j * 8 + jj;
                h[jj] = (_Float16)vv[idx >> 2][idx & 3];
            }
            *(f16x8*)&Pb[(size_t)q * 2048 + mb * 128 + c0 + j * 8] = h;
        }
        __syncthreads();   // S_lds reads done before next half overwrites
    }
}

// ---------------------------------------------------------------------------
// Kernel 4: out = scaled-P @ V. Double-buffered; grid.x = 64 combined,
// db = x>>4, nb = x&15 so the 4 db-siblings sharing a P panel have
// id == nb (mod 8) -> same XCD. Output fp32 [b][2048][512].
// ---------------------------------------------------------------------------
__global__ __launch_bounds__(256)
void out_kernel(const _Float16* __restrict__ P,
                const _Float16* __restrict__ Vt,
                const float2* __restrict__ ML,
                float* __restrict__ out, int b0)
{
    __shared__ _Float16 a0[128 * 64], a1[128 * 64];
    __shared__ _Float16 b0p[128 * 64], b1p[128 * 64];
    __shared__ float scale_lds[128][17];

    const int tid = threadIdx.x;
    const int db = blockIdx.x >> 4, nb = blockIdx.x & 15, bl = blockIdx.y;
    const int bg = b0 + bl;

    if (tid < 128) {
        const float2* mlrow = ML + ((size_t)bl * 2048 + nb * 128 + tid) * 16;
        float2 ml[16];
        float M = -3.4e38f;
#pragma unroll
        for (int t = 0; t < 16; t++) { ml[t] = mlrow[t]; M = fmaxf(M, ml[t].x); }
        float L = 0.0f;
#pragma unroll
        for (int t = 0; t < 16; t++) L += ml[t].y * exp2f((ml[t].x - M) * LOG2E);
        const float invL = 1.0f / L;
#pragma unroll
        for (int t = 0; t < 16; t++)
            scale_lds[tid][t] = exp2f((ml[t].x - M) * LOG2E) * invL;
    }

    const _Float16* Abase = P  + (size_t)bl * 2048 * 2048 + (size_t)(nb * 128) * 2048;
    const _Float16* Bbase = Vt + (size_t)bg * 512  * 2048 + (size_t)(db * 128) * 2048;

    const int lane = tid & 63;
    const int w = tid >> 6;
    const int wr = w >> 1, wc = w & 1;
    const int lrow = lane & 15, lkg = lane >> 4;

    f32x4 acc[4][4];
#pragma unroll
    for (int i = 0; i < 4; i++)
#pragma unroll
        for (int j = 0; j < 4; j++) acc[i][j] = (f32x4)0.0f;

    // prologue staging of tile 0 + scale_lds, one barrier
    stage128x64(Abase, 2048, a0, tid);
    stage128x64(Bbase, 2048, b0p, tid);
    __syncthreads();

    for (int t = 0; t < 32; ++t) {
        _Float16* acur = (t & 1) ? a1 : a0;
        _Float16* bcur = (t & 1) ? b1p : b0p;
        if (t + 1 < 32) {
            _Float16* anx = (t & 1) ? a0 : a1;
            _Float16* bnx = (t & 1) ? b0p : b1p;
            stage128x64(Abase + (size_t)(t + 1) * 64, 2048, anx, tid);
            stage128x64(Bbase + (size_t)(t + 1) * 64, 2048, bnx, tid);
        }
        const int kt = t >> 1;
#pragma unroll
        for (int kk = 0; kk < 2; kk++) {
            f16x8 af[4], bf[4];
#pragma unroll
            for (int mi = 0; mi < 4; mi++) {
                af[mi] = lds_frag(acur, wr * 64 + mi * 16 + lrow, kk * 32 + lkg * 8);
                const _Float16 hs = (_Float16)scale_lds[wr * 64 + mi * 16 + lrow][kt];
                af[mi] *= hs;
            }
#pragma unroll
            for (int ni = 0; ni < 4; ni++)
                bf[ni] = lds_frag(bcur, wc * 64 + ni * 16 + lrow, kk * 32 + lkg * 8);
#pragma unroll
            for (int mi = 0; mi < 4; mi++)
#pragma unroll
                for (int ni = 0; ni < 4; ni++)
                    acc[mi][ni] = __builtin_amdgcn_mfma_f32_16x16x32_f16(af[mi], bf[ni], acc[mi][ni], 0, 0, 0);
        }
        __syncthreads();
    }

#pragma unroll
    for (int mi = 0; mi < 4; mi++) {
        const int nbase = nb * 128 + wr * 64 + mi * 16 + lkg * 4;
#pragma unroll
        for (int ni = 0; ni < 4; ni++) {
            const int d = db * 128 + wc * 64 + ni * 16 + lrow;
#pragma unroll
            for (int rr = 0; rr < 4; rr++)
                out[((size_t)bg * 2048 + nbase + rr) * 512 + d] = acc[mi][ni][rr];
        }
    }
}

// ---------------------------------------------------------------------------
extern "C" void kernel_launch(void* const* d_in, const int* in_sizes, int n_in,
                              void* d_out, int out_size, void* d_ws, size_t ws_size,
                              hipStream_t stream) {
    const float* x  = (const float*)d_in[0];
    const float* Wq = (const float*)d_in[1];
    const float* Wk = (const float*)d_in[2];
    const float* Wv = (const float*)d_in[3];

    const size_t MB = 1024ull * 1024ull;
    char* ws = (char*)d_ws;
    _Float16* Qf = (_Float16*)ws;                                  // 16 MB
    _Float16* Kf = Qf + (size_t)16384 * 512;                       // 16 MB
    _Float16* Vt = Kf + (size_t)16384 * 512;                       // 16 MB
    _Float16* P  = Vt + (size_t)16384 * 512;                       // chunk * 8 MB
    float*    out = (float*)d_out;

    int chunk;
    if      (ws_size >= 120 * MB) chunk = 8;
    else if (ws_size >= 88  * MB) chunk = 4;
    else if (ws_size >= 70  * MB) chunk = 2;
    else                          chunk = 1;

    float2* ML = (float2*)(P + (size_t)chunk * 2048 * 2048);       // chunk * 256 KB

    // Aliases into the P/ML region (dead until score_kernel runs):
    _Float16* xh = (_Float16*)P;                    // 16 MB
    _Float16* Wt = xh + (size_t)16384 * 512;        // 1.5 MB  (needs ws >= 65.5 MB)

    convert_kernel<<<2816, 256, 0, stream>>>(x, Wq, Wk, Wv, xh, Wt);
    proj_kernel<<<dim3(128, 12), 256, 0, stream>>>(xh, Wt, Qf, Kf, Vt);

    for (int b0 = 0; b0 < 8; b0 += chunk) {
        score_kernel<<<dim3(16, 16, chunk), 256, 0, stream>>>(Qf, Kf, P, ML, b0);
        out_kernel<<<dim3(64, chunk), 256, 0, stream>>>(P, Vt, ML, out, b0);
    }
}

// Round 8
// 141.963 us; speedup vs baseline: 1.6049x; 1.1216x over previous
//
#include <hip/hip_runtime.h>
#include <hip/hip_fp16.h>

typedef _Float16 f16x8 __attribute__((ext_vector_type(8)));
typedef _Float16 f16x4 __attribute__((ext_vector_type(4)));
typedef float    f32x4 __attribute__((ext_vector_type(4)));

#define LOG2E 1.44269504f

// ---------------------------------------------------------------------------
// Staging: 128 rows x 64 halves fp16 tile -> 16 KB linear LDS via
// global_load_lds dwordx4 (4 wave-instrs/thread => 4 vmcnt events/wave).
// Source col pre-swizzled (byte ^= (row&7)<<4); readers apply same XOR.
// ---------------------------------------------------------------------------
__device__ __forceinline__ void stage128x64(const _Float16* __restrict__ g, int ld,
                                            void* lds, int tid)
{
    const int r0   = tid >> 3;
    const int colh = ((tid & 7) ^ (r0 & 7)) << 3;
    char* lbase = (char*)lds + (tid >> 6) * 1024;
#pragma unroll
    for (int i = 0; i < 4; i++) {
        const _Float16* src = g + (size_t)(i * 32 + r0) * ld + colh;
        __builtin_amdgcn_global_load_lds(
            (const __attribute__((address_space(1))) void*)src,
            (__attribute__((address_space(3))) void*)(lbase + i * 4096),
            16, 0, 0);
    }
}

__device__ __forceinline__ f16x8 lds_frag(const void* lds, int row, int colh)
{
    const int off = row * 128 + ((colh * 2) ^ ((row & 7) << 4));
    return *(const f16x8*)((const char*)lds + off);
}

// ---------------------------------------------------------------------------
// Counted-vmcnt depth-2 pipelined GEMM loop (T4). Per iter t:
//  (a) ds_read ALL tile-t fragments -> regs   [slot t&1]
//  (b) lgkmcnt(0) + sched_barrier  (rule #18)
//  (c) s_barrier                   -> slot t&1 dead for ALL waves
//  (d) stage tile t+2 -> slot t&1  (8 vmem instrs/wave, stay in flight)
//  (e) MFMA from regs (setprio)
//  (f) vmcnt(8): tile t+1's loads (issued LAST iter) done; t+2's in flight
//  (g) s_barrier
// ---------------------------------------------------------------------------
template<int NK>
__device__ __forceinline__ void gemm_loop_cv(const _Float16* __restrict__ A, int lda,
                                             const _Float16* __restrict__ B, int ldb,
                                             _Float16* a0, _Float16* a1,
                                             _Float16* b0, _Float16* b1,
                                             f32x4 acc[4][4], int tid,
                                             int wr, int wc, int lrow, int lkg)
{
    stage128x64(A, lda, a0, tid);
    stage128x64(B, ldb, b0, tid);
    stage128x64(A + 64, lda, a1, tid);
    stage128x64(B + 64, ldb, b1, tid);
    asm volatile("s_waitcnt vmcnt(8)" ::: "memory");   // tile0 landed
    __builtin_amdgcn_s_barrier();
    __builtin_amdgcn_sched_barrier(0);

    for (int t = 0; t < NK; ++t) {
        _Float16* acur = (t & 1) ? a1 : a0;
        _Float16* bcur = (t & 1) ? b1 : b0;

        f16x8 af[2][4], bf[2][4];
#pragma unroll
        for (int kk = 0; kk < 2; kk++) {
#pragma unroll
            for (int mi = 0; mi < 4; mi++)
                af[kk][mi] = lds_frag(acur, wr * 64 + mi * 16 + lrow, kk * 32 + lkg * 8);
#pragma unroll
            for (int ni = 0; ni < 4; ni++)
                bf[kk][ni] = lds_frag(bcur, wc * 64 + ni * 16 + lrow, kk * 32 + lkg * 8);
        }
        asm volatile("s_waitcnt lgkmcnt(0)" ::: "memory");
        __builtin_amdgcn_sched_barrier(0);
        __builtin_amdgcn_s_barrier();

        if (t + 2 < NK) {
            stage128x64(A + (size_t)(t + 2) * 64, lda, acur, tid);
            stage128x64(B + (size_t)(t + 2) * 64, ldb, bcur, tid);
        }
        __builtin_amdgcn_sched_barrier(0);

        __builtin_amdgcn_s_setprio(1);
#pragma unroll
        for (int kk = 0; kk < 2; kk++)
#pragma unroll
            for (int mi = 0; mi < 4; mi++)
#pragma unroll
                for (int ni = 0; ni < 4; ni++)
                    acc[mi][ni] = __builtin_amdgcn_mfma_f32_16x16x32_f16(
                        af[kk][mi], bf[kk][ni], acc[mi][ni], 0, 0, 0);
        __builtin_amdgcn_s_setprio(0);

        if (t + 2 < NK) asm volatile("s_waitcnt vmcnt(8)" ::: "memory");
        else            asm volatile("s_waitcnt vmcnt(0)" ::: "memory");
        __builtin_amdgcn_sched_barrier(0);
        __builtin_amdgcn_s_barrier();
        __builtin_amdgcn_sched_barrier(0);
    }
}

// ---------------------------------------------------------------------------
// Kernel 0: convert x -> fp16 xh; W{q,k,v} -> fp16 transposed Wt[3][n][k].
// ---------------------------------------------------------------------------
__global__ __launch_bounds__(256)
void convert_kernel(const float* __restrict__ x,
                    const float* __restrict__ Wq,
                    const float* __restrict__ Wk,
                    const float* __restrict__ Wv,
                    _Float16* __restrict__ xh,
                    _Float16* __restrict__ Wt)
{
    const int b = blockIdx.x;
    if (b < 2048) {
        const size_t base = (size_t)b * 4096 + (size_t)threadIdx.x * 4;
#pragma unroll
        for (int i = 0; i < 4; i++) {
            f32x4 v = *(const f32x4*)(x + base + i * 1024);
            f16x4 h;
#pragma unroll
            for (int j = 0; j < 4; j++) h[j] = (_Float16)v[j];
            *(f16x4*)(xh + base + i * 1024) = h;
        }
    } else {
        __shared__ float tb[32][33];
        const int t = b - 2048;
        const int mat = t >> 8;
        const int tile = t & 255;
        const int tr = tile >> 4, tc = tile & 15;
        const float* W = (mat == 0) ? Wq : (mat == 1) ? Wk : Wv;
        const int r = threadIdx.x >> 5, c = threadIdx.x & 31;
#pragma unroll
        for (int p = 0; p < 4; p++)
            tb[p * 8 + r][c] = W[(size_t)(tr * 32 + p * 8 + r) * 512 + tc * 32 + c];
        __syncthreads();
#pragma unroll
        for (int p = 0; p < 4; p++)
            Wt[((size_t)mat * 512 + tc * 32 + p * 8 + r) * 512 + tr * 32 + c] =
                (_Float16)tb[c][p * 8 + r];
    }
}

// ---------------------------------------------------------------------------
// Kernel 1: QKV projection (all-fp16). Q,K row-major; V transposed [b][d][m].
// grid (mb=128 x, cb=12 y) for XCD-shared xh panels.
// ---------------------------------------------------------------------------
__global__ __launch_bounds__(256, 2)
void proj_kernel(const _Float16* __restrict__ xh,
                 const _Float16* __restrict__ Wt,
                 _Float16* __restrict__ Qf,
                 _Float16* __restrict__ Kf,
                 _Float16* __restrict__ Vt)
{
    __shared__ _Float16 a0[128 * 64], a1[128 * 64];
    __shared__ _Float16 b0[128 * 64], b1[128 * 64];

    const int tid = threadIdx.x;
    const int mb = blockIdx.x, cb = blockIdx.y;
    const int mat = cb >> 2, nb = cb & 3;
    const int m0 = mb * 128, n0 = nb * 128;

    const _Float16* Abase = xh + (size_t)m0 * 512;
    const _Float16* Bbase = Wt + ((size_t)mat * 512 + n0) * 512;

    const int lane = tid & 63;
    const int w = tid >> 6;
    const int wr = w >> 1, wc = w & 1;
    const int lrow = lane & 15, lkg = lane >> 4;

    f32x4 acc[4][4];
#pragma unroll
    for (int i = 0; i < 4; i++)
#pragma unroll
        for (int j = 0; j < 4; j++) acc[i][j] = (f32x4)0.0f;

    gemm_loop_cv<8>(Abase, 512, Bbase, 512, a0, a1, b0, b1,
                    acc, tid, wr, wc, lrow, lkg);

    if (mat < 2) {
        _Float16* Out = (mat == 0) ? Qf : Kf;
#pragma unroll
        for (int mi = 0; mi < 4; mi++) {
            const int mbase = m0 + wr * 64 + mi * 16 + lkg * 4;
#pragma unroll
            for (int ni = 0; ni < 4; ni++) {
                const int ncol = n0 + wc * 64 + ni * 16 + lrow;
#pragma unroll
                for (int r = 0; r < 4; r++)
                    Out[(size_t)(mbase + r) * 512 + ncol] = (_Float16)acc[mi][ni][r];
            }
        }
    } else {
#pragma unroll
        for (int mi = 0; mi < 4; mi++) {
            const int mglob = m0 + wr * 64 + mi * 16 + lkg * 4;
            const int b = mglob >> 11, mloc = mglob & 2047;
#pragma unroll
            for (int ni = 0; ni < 4; ni++) {
                const int d = n0 + wc * 64 + ni * 16 + lrow;
                f16x4 h;
#pragma unroll
                for (int r = 0; r < 4; r++) h[r] = (_Float16)acc[mi][ni][r];
                *(f16x4*)&Vt[((size_t)b * 512 + d) * 2048 + mloc] = h;
            }
        }
    }
}

// ---------------------------------------------------------------------------
// Kernel 2: S-tile = Q @ K^T (counted-vmcnt loop), LDS-transpose softmax
// epilogue. S_lds (33 KB fp32) aliases the 64 KB slot buffers (dead after
// the loop's final barrier). grid (mb 16, nb 16, chunk).
// ---------------------------------------------------------------------------
__global__ __launch_bounds__(256, 2)
void score_kernel(const _Float16* __restrict__ Qf,
                  const _Float16* __restrict__ Kf,
                  _Float16* __restrict__ P,
                  float2* __restrict__ ML, int b0)
{
    __shared__ __align__(16) char smem[65536];
    _Float16* a0  = (_Float16*)smem;
    _Float16* a1  = (_Float16*)(smem + 16384);
    _Float16* b0p = (_Float16*)(smem + 32768);
    _Float16* b1p = (_Float16*)(smem + 49152);
    float (*S_lds)[132] = (float(*)[132])smem;     // 33792 B, aliases buffers

    const int tid = threadIdx.x;
    const int mb = blockIdx.x, nb = blockIdx.y, bl = blockIdx.z;
    const int bg = b0 + bl;

    const _Float16* Abase = Qf + (size_t)(bg * 2048 + nb * 128) * 512;
    const _Float16* Bbase = Kf + (size_t)(bg * 2048 + mb * 128) * 512;

    const int lane = tid & 63;
    const int w = tid >> 6;
    const int wr = w >> 1, wc = w & 1;
    const int lrow = lane & 15, lkg = lane >> 4;

    f32x4 acc[4][4];
#pragma unroll
    for (int i = 0; i < 4; i++)
#pragma unroll
        for (int j = 0; j < 4; j++) acc[i][j] = (f32x4)0.0f;

    gemm_loop_cv<8>(Abase, 512, Bbase, 512, a0, a1, b0p, b1p,
                    acc, tid, wr, wc, lrow, lkg);
    // final s_barrier: all waves' LDS reads in regs -> S_lds reuse safe

    _Float16* Pb = P + (size_t)bl * 2048 * 2048;
    const int s  = tid >> 2;          // 0..63: S_lds row this thread reduces
    const int c0 = (tid & 3) * 32;    // col span start

#pragma unroll
    for (int hp = 0; hp < 2; hp++) {
        // ---- scatter this half's acc quadrants into S_lds ----
#pragma unroll
        for (int m2 = 0; m2 < 2; m2++) {
            const int mi = hp * 2 + m2;
            const int srow = wr * 32 + m2 * 16 + lkg * 4;
#pragma unroll
            for (int ni = 0; ni < 4; ni++) {
                const int col = wc * 64 + ni * 16 + lrow;
#pragma unroll
                for (int rr = 0; rr < 4; rr++)
                    S_lds[srow + rr][col] = acc[mi][ni][rr];
            }
        }
        __syncthreads();

        // ---- row-contiguous re-read: 4 threads per row, 32 cols each ----
        f32x4 vv[8];
#pragma unroll
        for (int j = 0; j < 8; j++)
            vv[j] = *(const f32x4*)&S_lds[s][c0 + j * 4];

        float m = vv[0][0];
#pragma unroll
        for (int j = 0; j < 8; j++)
#pragma unroll
            for (int jj = 0; jj < 4; jj++) m = fmaxf(m, vv[j][jj]);
        m = fmaxf(m, __shfl_xor(m, 1));
        m = fmaxf(m, __shfl_xor(m, 2));

        float l = 0.0f;
#pragma unroll
        for (int j = 0; j < 8; j++)
#pragma unroll
            for (int jj = 0; jj < 4; jj++) {
                float e = exp2f((vv[j][jj] - m) * LOG2E);
                vv[j][jj] = e;
                l += e;
            }
        l += __shfl_xor(l, 1);
        l += __shfl_xor(l, 2);

        const int q_local = (s >> 5) * 64 + hp * 32 + (s & 31);
        const int q = nb * 128 + q_local;

        if ((tid & 3) == 0) {
            float2 v; v.x = m; v.y = l;
            ML[((size_t)bl * 2048 + q) * 16 + mb] = v;
        }

        // ---- pack fp16, coalesced dwordx4 stores ----
#pragma unroll
        for (int j = 0; j < 4; j++) {
            f16x8 h;
#pragma unroll
            for (int jj = 0; jj < 8; jj++) {
                const int idx = j * 8 + jj;
                h[jj] = (_Float16)vv[idx >> 2][idx & 3];
            }
            *(f16x8*)&Pb[(size_t)q * 2048 + mb * 128 + c0 + j * 8] = h;
        }
        __syncthreads();   // S_lds reads done before next half overwrites
    }
}

// ---------------------------------------------------------------------------
// Kernel 4: out = scaled-P @ V, counted-vmcnt loop with per-ktile scale on
// the A fragments (read into regs in phase (a)). grid.x = 64 (db=x>>4,
// nb=x&15 for XCD-shared P panels). Output fp32 [b][2048][512].
// ---------------------------------------------------------------------------
__global__ __launch_bounds__(256, 2)
void out_kernel(const _Float16* __restrict__ P,
                const _Float16* __restrict__ Vt,
                const float2* __restrict__ ML,
                float* __restrict__ out, int b0)
{
    __shared__ _Float16 a0[128 * 64], a1[128 * 64];
    __shared__ _Float16 b0p[128 * 64], b1p[128 * 64];
    __shared__ float scale_lds[128][17];

    const int tid = threadIdx.x;
    const int db = blockIdx.x >> 4, nb = blockIdx.x & 15, bl = blockIdx.y;
    const int bg = b0 + bl;

    if (tid < 128) {
        const float2* mlrow = ML + ((size_t)bl * 2048 + nb * 128 + tid) * 16;
        float2 ml[16];
        float M = -3.4e38f;
#pragma unroll
        for (int t = 0; t < 16; t++) { ml[t] = mlrow[t]; M = fmaxf(M, ml[t].x); }
        float L = 0.0f;
#pragma unroll
        for (int t = 0; t < 16; t++) L += ml[t].y * exp2f((ml[t].x - M) * LOG2E);
        const float invL = 1.0f / L;
#pragma unroll
        for (int t = 0; t < 16; t++)
            scale_lds[tid][t] = exp2f((ml[t].x - M) * LOG2E) * invL;
    }

    const _Float16* Abase = P  + (size_t)bl * 2048 * 2048 + (size_t)(nb * 128) * 2048;
    const _Float16* Bbase = Vt + (size_t)bg * 512  * 2048 + (size_t)(db * 128) * 2048;

    const int lane = tid & 63;
    const int w = tid >> 6;
    const int wr = w >> 1, wc = w & 1;
    const int lrow = lane & 15, lkg = lane >> 4;

    f32x4 acc[4][4];
#pragma unroll
    for (int i = 0; i < 4; i++)
#pragma unroll
        for (int j = 0; j < 4; j++) acc[i][j] = (f32x4)0.0f;

    __syncthreads();   // scale_lds ready; drains prologue ML loads (vmcnt 0)

    // pipeline prologue
    stage128x64(Abase,      2048, a0,  tid);
    stage128x64(Bbase,      2048, b0p, tid);
    stage128x64(Abase + 64, 2048, a1,  tid);
    stage128x64(Bbase + 64, 2048, b1p, tid);
    asm volatile("s_waitcnt vmcnt(8)" ::: "memory");
    __builtin_amdgcn_s_barrier();
    __builtin_amdgcn_sched_barrier(0);

    for (int t = 0; t < 32; ++t) {
        _Float16* acur = (t & 1) ? a1 : a0;
        _Float16* bcur = (t & 1) ? b1p : b0p;
        const int kt = t >> 1;

        f16x8 af[2][4], bf[2][4];
        float sc[4];
#pragma unroll
        for (int kk = 0; kk < 2; kk++) {
#pragma unroll
            for (int mi = 0; mi < 4; mi++)
                af[kk][mi] = lds_frag(acur, wr * 64 + mi * 16 + lrow, kk * 32 + lkg * 8);
#pragma unroll
            for (int ni = 0; ni < 4; ni++)
                bf[kk][ni] = lds_frag(bcur, wc * 64 + ni * 16 + lrow, kk * 32 + lkg * 8);
        }
#pragma unroll
        for (int mi = 0; mi < 4; mi++)
            sc[mi] = scale_lds[wr * 64 + mi * 16 + lrow][kt];
        asm volatile("s_waitcnt lgkmcnt(0)" ::: "memory");
        __builtin_amdgcn_sched_barrier(0);
        __builtin_amdgcn_s_barrier();

        if (t + 2 < 32) {
            stage128x64(Abase + (size_t)(t + 2) * 64, 2048, acur, tid);
            stage128x64(Bbase + (size_t)(t + 2) * 64, 2048, bcur, tid);
        }
        __builtin_amdgcn_sched_barrier(0);

        __builtin_amdgcn_s_setprio(1);
#pragma unroll
        for (int kk = 0; kk < 2; kk++)
#pragma unroll
            for (int mi = 0; mi < 4; mi++) {
                const f16x8 a = af[kk][mi] * (_Float16)sc[mi];
#pragma unroll
                for (int ni = 0; ni < 4; ni++)
                    acc[mi][ni] = __builtin_amdgcn_mfma_f32_16x16x32_f16(
                        a, bf[kk][ni], acc[mi][ni], 0, 0, 0);
            }
        __builtin_amdgcn_s_setprio(0);

        if (t + 2 < 32) asm volatile("s_waitcnt vmcnt(8)" ::: "memory");
        else            asm volatile("s_waitcnt vmcnt(0)" ::: "memory");
        __builtin_amdgcn_sched_barrier(0);
        __builtin_amdgcn_s_barrier();
        __builtin_amdgcn_sched_barrier(0);
    }

#pragma unroll
    for (int mi = 0; mi < 4; mi++) {
        const int nbase = nb * 128 + wr * 64 + mi * 16 + lkg * 4;
#pragma unroll
        for (int ni = 0; ni < 4; ni++) {
            const int d = db * 128 + wc * 64 + ni * 16 + lrow;
#pragma unroll
            for (int rr = 0; rr < 4; rr++)
                out[((size_t)bg * 2048 + nbase + rr) * 512 + d] = acc[mi][ni][rr];
        }
    }
}

// ---------------------------------------------------------------------------
extern "C" void kernel_launch(void* const* d_in, const int* in_sizes, int n_in,
                              void* d_out, int out_size, void* d_ws, size_t ws_size,
                              hipStream_t stream) {
    const float* x  = (const float*)d_in[0];
    const float* Wq = (const float*)d_in[1];
    const float* Wk = (const float*)d_in[2];
    const float* Wv = (const float*)d_in[3];

    const size_t MB = 1024ull * 1024ull;
    char* ws = (char*)d_ws;
    _Float16* Qf = (_Float16*)ws;                                  // 16 MB
    _Float16* Kf = Qf + (size_t)16384 * 512;                       // 16 MB
    _Float16* Vt = Kf + (size_t)16384 * 512;                       // 16 MB
    _Float16* P  = Vt + (size_t)16384 * 512;                       // chunk * 8 MB
    float*    out = (float*)d_out;

    int chunk;
    if      (ws_size >= 120 * MB) chunk = 8;
    else if (ws_size >= 88  * MB) chunk = 4;
    else if (ws_size >= 70  * MB) chunk = 2;
    else                          chunk = 1;

    float2* ML = (float2*)(P + (size_t)chunk * 2048 * 2048);       // chunk * 256 KB

    // Aliases into the P/ML region (dead until score_kernel runs):
    _Float16* xh = (_Float16*)P;                    // 16 MB
    _Float16* Wt = xh + (size_t)16384 * 512;        // 1.5 MB

    convert_kernel<<<2816, 256, 0, stream>>>(x, Wq, Wk, Wv, xh, Wt);
    proj_kernel<<<dim3(128, 12), 256, 0, stream>>>(xh, Wt, Qf, Kf, Vt);

    for (int b0 = 0; b0 < 8; b0 += chunk) {
        score_kernel<<<dim3(16, 16, chunk), 256, 0, stream>>>(Qf, Kf, P, ML, b0);
        out_kernel<<<dim3(64, chunk), 256, 0, stream>>>(P, Vt, ML, out, b0);
    }
}